// Round 1
// baseline (1301.844 us; speedup 1.0000x reference)
//
#include <hip/hip_runtime.h>
#include <hip/hip_bf16.h>

// Shapes (compile-time constants from the reference)
// EMBED=HIDDEN=512, VOCAB=30000, B=16, S=128, K=49, NT=5, rows BS=2048

// ---------------------------------------------------------------------------
// K1: Zh = h_t @ W_Zh.T + b_Zh   (2048,49)  ; Qh = h_t @ W_Qh.T + b_Qh (2048,5)
__global__ void k_lin_h(const float* __restrict__ h,
                        const float* __restrict__ W_Zh, const float* __restrict__ b_Zh,
                        const float* __restrict__ W_Qh, const float* __restrict__ b_Qh,
                        float* __restrict__ Zh, float* __restrict__ Qh)
{
    __shared__ float hs[512];
    const int row = blockIdx.x;
    const float* hp = h + row * 512;
    for (int i = threadIdx.x; i < 512; i += 256) hs[i] = hp[i];
    __syncthreads();
    const int t = threadIdx.x;
    if (t < 49) {
        const float* w = W_Zh + t * 512;
        float acc = b_Zh[t];
        #pragma unroll 8
        for (int i = 0; i < 512; ++i) acc = fmaf(hs[i], w[i], acc);
        Zh[row * 64 + t] = acc;
    } else if (t >= 64 && t < 69) {
        const int o = t - 64;
        const float* w = W_Qh + o * 512;
        float acc = b_Qh[o];
        #pragma unroll 8
        for (int i = 0; i < 512; ++i) acc = fmaf(hs[i], w[i], acc);
        Qh[row * 8 + o] = acc;
    }
}

// ---------------------------------------------------------------------------
// K2: ZV = V @ W_ZV.T + b_ZV  (16*49,49) ; QT = T @ W_QT.T + b_QT (16*5,5)
__global__ void k_lin_vt(const float* __restrict__ V,
                         const float* __restrict__ W_ZV, const float* __restrict__ b_ZV,
                         const float* __restrict__ T,
                         const float* __restrict__ W_QT, const float* __restrict__ b_QT,
                         float* __restrict__ ZV, float* __restrict__ QT)
{
    __shared__ float xs[512];
    const int blk = blockIdx.x;
    const int t = threadIdx.x;
    if (blk < 784) {                      // V rows: b*49+k
        const float* xp = V + (size_t)blk * 512;
        for (int i = t; i < 512; i += 256) xs[i] = xp[i];
        __syncthreads();
        if (t < 49) {
            const float* w = W_ZV + t * 512;
            float acc = b_ZV[t];
            #pragma unroll 8
            for (int i = 0; i < 512; ++i) acc = fmaf(xs[i], w[i], acc);
            ZV[blk * 64 + t] = acc;
        }
    } else {                              // T rows: b*5+nt
        const int row = blk - 784;
        const float* xp = T + (size_t)row * 512;
        for (int i = t; i < 512; i += 256) xs[i] = xp[i];
        __syncthreads();
        if (t < 5) {
            const float* w = W_QT + t * 512;
            float acc = b_QT[t];
            #pragma unroll 8
            for (int i = 0; i < 512; ++i) acc = fmaf(xs[i], w[i], acc);
            QT[row * 8 + t] = acc;
        }
    }
}

// ---------------------------------------------------------------------------
// K3: per (b,s): visual + topic attention -> z_t (2048,512), q_t (2048,512)
__global__ void k_attn(const float* __restrict__ V, const float* __restrict__ T,
                       const float* __restrict__ ZV, const float* __restrict__ Zh,
                       const float* __restrict__ QT, const float* __restrict__ Qh,
                       const float* __restrict__ W_az, const float* __restrict__ b_az,
                       const float* __restrict__ W_bq, const float* __restrict__ b_bq,
                       float* __restrict__ z_t, float* __restrict__ q_t)
{
    const int row = blockIdx.x;       // b*128+s
    const int b = row >> 7;
    const int t = threadIdx.x;
    __shared__ float zh[49], waz[49], alpha[49], beta[5];
    if (t < 49) { zh[t] = Zh[row * 64 + t]; waz[t] = W_az[t]; }
    __syncthreads();
    if (t < 49) {
        const float* zv = ZV + (b * 49 + t) * 64;
        float acc = b_az[0];
        for (int j = 0; j < 49; ++j) acc += tanhf(zv[j] + zh[j]) * waz[j];
        alpha[t] = acc;
    } else if (t >= 64 && t < 69) {
        const int tt = t - 64;
        const float* qt = QT + (b * 5 + tt) * 8;
        const float* qh = Qh + row * 8;
        float acc = b_bq[0];
        for (int j = 0; j < 5; ++j) acc += tanhf(qt[j] + qh[j]) * W_bq[j];
        beta[tt] = acc;
    }
    __syncthreads();
    if (t == 0) {          // softmax over 49 (wave 0)
        float m = -1e30f;
        for (int k = 0; k < 49; ++k) m = fmaxf(m, alpha[k]);
        float s = 0.f;
        for (int k = 0; k < 49; ++k) { alpha[k] = expf(alpha[k] - m); s += alpha[k]; }
        float inv = 1.f / s;
        for (int k = 0; k < 49; ++k) alpha[k] *= inv;
    } else if (t == 64) {  // softmax over 5 (wave 1, parallel)
        float m = -1e30f;
        for (int k = 0; k < 5; ++k) m = fmaxf(m, beta[k]);
        float s = 0.f;
        for (int k = 0; k < 5; ++k) { beta[k] = expf(beta[k] - m); s += beta[k]; }
        float inv = 1.f / s;
        for (int k = 0; k < 5; ++k) beta[k] *= inv;
    }
    __syncthreads();
    const float* Vb = V + (size_t)b * 49 * 512;
    const float* Tb = T + (size_t)b * 5 * 512;
    for (int hd = t; hd < 512; hd += 256) {
        float az = 0.f;
        #pragma unroll
        for (int k = 0; k < 49; ++k) az = fmaf(alpha[k], Vb[k * 512 + hd], az);
        z_t[(size_t)row * 512 + hd] = az;
        float aq = 0.f;
        #pragma unroll
        for (int k = 0; k < 5; ++k) aq = fmaf(beta[k], Tb[k * 512 + hd], aq);
        q_t[(size_t)row * 512 + hd] = aq;
    }
}

// ---------------------------------------------------------------------------
// Tiled fp32 GEMM:  C[M,N] = act( A@W.T (+ A2@W2.T) + bias (+ bias2) )
// A row-major (M,K), W row-major (N,K). 64x64 tile, 4x4 per thread, BK=32.
template<int ACT, bool DUAL, bool NB>
__global__ __launch_bounds__(256) void k_gemm_nt(
    const float* __restrict__ A, const float* __restrict__ W,
    const float* __restrict__ A2, const float* __restrict__ W2,
    const float* __restrict__ bias, const float* __restrict__ bias2,
    float* __restrict__ C, int M, int N, int K)
{
    __shared__ __align__(16) float As[32][68];   // k-major, 16B-aligned rows
    __shared__ __align__(16) float Ws[32][68];
    const int tid = threadIdx.x;
    const int tx = tid & 15, ty = tid >> 4;
    const int m0 = blockIdx.y * 64, n0 = blockIdx.x * 64;
    float acc[4][4] = {};
    const int npass = DUAL ? 2 : 1;
    for (int pass = 0; pass < npass; ++pass) {
        const float* Ap = (DUAL && pass) ? A2 : A;
        const float* Wp = (DUAL && pass) ? W2 : W;
        for (int k0 = 0; k0 < K; k0 += 32) {
            #pragma unroll
            for (int e = 0; e < 8; ++e) {
                const int idx = tid + e * 256;
                const int r = idx >> 5, c = idx & 31;
                As[c][r] = Ap[(size_t)(m0 + r) * K + k0 + c];
                float wv = 0.f;
                const int nr = n0 + r;
                if (!NB || nr < N) wv = Wp[(size_t)nr * K + k0 + c];
                Ws[c][r] = wv;
            }
            __syncthreads();
            #pragma unroll
            for (int kk = 0; kk < 32; ++kk) {
                const float4 av = *(const float4*)(&As[kk][ty << 2]);
                const float4 wv = *(const float4*)(&Ws[kk][tx << 2]);
                const float a[4] = {av.x, av.y, av.z, av.w};
                const float w[4] = {wv.x, wv.y, wv.z, wv.w};
                #pragma unroll
                for (int i = 0; i < 4; ++i)
                    #pragma unroll
                    for (int j = 0; j < 4; ++j)
                        acc[i][j] = fmaf(a[i], w[j], acc[i][j]);
            }
            __syncthreads();
        }
    }
    #pragma unroll
    for (int i = 0; i < 4; ++i) {
        const int m = m0 + (ty << 2) + i;
        #pragma unroll
        for (int j = 0; j < 4; ++j) {
            const int n = n0 + (tx << 2) + j;
            if (NB && n >= N) continue;
            float v = acc[i][j] + bias[n];
            if (DUAL) v += bias2[n];
            if (ACT == 1) v = tanhf(v);
            C[(size_t)m * N + n] = v;
        }
    }
}

// ---------------------------------------------------------------------------
// K6: sentinel gate (batch 0 only, diagonal) -> gama[128]
__global__ void k_sentinel(const float* __restrict__ s_t, const float* __restrict__ r_t,
                           const float* __restrict__ Qh,
                           const float* __restrict__ W_Ss, const float* __restrict__ b_Ss,
                           const float* __restrict__ W_Sr, const float* __restrict__ b_Sr,
                           const float* __restrict__ W_bq, const float* __restrict__ b_bq,
                           const int* __restrict__ epoch, float* __restrict__ gama)
{
    const int s = threadIdx.x;   // 0..127
    if (epoch[0] <= 20) { gama[s] = 1.0f; return; }
    const float* sp = s_t + (size_t)s * 512;   // batch 0 row s
    const float* rp = r_t + (size_t)s * 512;
    const float* qh = Qh + s * 8;              // row = 0*128+s
    float accs[5] = {}, accr[5] = {};
    for (int i = 0; i < 512; ++i) {
        const float sv = sp[i], rv = rp[i];
        #pragma unroll
        for (int t = 0; t < 5; ++t) {
            accs[t] = fmaf(sv, W_Ss[t * 512 + i], accs[t]);
            accr[t] = fmaf(rv, W_Sr[t * 512 + i], accr[t]);
        }
    }
    float ss = b_bq[0], sr = b_bq[0];
    #pragma unroll
    for (int t = 0; t < 5; ++t) {
        ss += tanhf(accs[t] + b_Ss[t] + qh[t]) * W_bq[t];
        sr += tanhf(accr[t] + b_Sr[t] + qh[t]) * W_bq[t];
    }
    gama[s] = 1.f / (1.f + expf(-(ss - sr)));
}

// ---------------------------------------------------------------------------
// K7: c_t = gama*s_t + (1-gama)*r_t
__global__ void k_blend(const float* __restrict__ s_t, const float* __restrict__ r_t,
                        const float* __restrict__ gama, float* __restrict__ c_t)
{
    const int row = blockIdx.x;
    const float g = gama[row & 127];
    const size_t base = (size_t)row * 512;
    for (int i = threadIdx.x; i < 512; i += 256)
        c_t[base + i] = g * s_t[base + i] + (1.f - g) * r_t[base + i];
}

// ---------------------------------------------------------------------------
extern "C" void kernel_launch(void* const* d_in, const int* in_sizes, int n_in,
                              void* d_out, int out_size, void* d_ws, size_t ws_size,
                              hipStream_t stream)
{
    const int*   epoch = (const int*)  d_in[0];
    const float* h_t   = (const float*)d_in[1];
    const float* V     = (const float*)d_in[2];
    const float* T     = (const float*)d_in[3];
    const float* W_ZV  = (const float*)d_in[4];  const float* b_ZV = (const float*)d_in[5];
    const float* W_Zh  = (const float*)d_in[6];  const float* b_Zh = (const float*)d_in[7];
    const float* W_az  = (const float*)d_in[8];  const float* b_az = (const float*)d_in[9];
    const float* W_QT  = (const float*)d_in[10]; const float* b_QT = (const float*)d_in[11];
    const float* W_Qh  = (const float*)d_in[12]; const float* b_Qh = (const float*)d_in[13];
    const float* W_bq  = (const float*)d_in[14]; const float* b_bq = (const float*)d_in[15];
    const float* W_sq  = (const float*)d_in[16]; const float* b_sq = (const float*)d_in[17];
    const float* W_sh  = (const float*)d_in[18]; const float* b_sh = (const float*)d_in[19];
    const float* W_Ss  = (const float*)d_in[20]; const float* b_Ss = (const float*)d_in[21];
    const float* W_Sr  = (const float*)d_in[22]; const float* b_Sr = (const float*)d_in[23];
    const float* W_sz  = (const float*)d_in[24]; const float* b_sz = (const float*)d_in[25];
    const float* W_mlp = (const float*)d_in[26]; const float* b_mlp= (const float*)d_in[27];

    float* out = (float*)d_out;
    float* ws  = (float*)d_ws;
    const size_t R = 2048 * 512;
    float* z_t  = ws;
    float* q_t  = ws + R;
    float* r_t  = ws + 2 * R;
    float* s_t  = ws + 3 * R;
    float* c_t  = ws + 4 * R;
    float* Zh   = ws + 5 * R;        // 2048*64
    float* ZV   = Zh + 2048 * 64;    // 784*64
    float* Qh   = ZV + 784 * 64;     // 2048*8
    float* QT   = Qh + 2048 * 8;     // 80*8
    float* gama = QT + 80 * 8;       // 128

    k_lin_h<<<2048, 256, 0, stream>>>(h_t, W_Zh, b_Zh, W_Qh, b_Qh, Zh, Qh);
    k_lin_vt<<<864, 256, 0, stream>>>(V, W_ZV, b_ZV, T, W_QT, b_QT, ZV, QT);
    k_attn<<<2048, 256, 0, stream>>>(V, T, ZV, Zh, QT, Qh, W_az, b_az, W_bq, b_bq, z_t, q_t);
    // r_t = tanh(z_t @ W_sz.T + b_sz)
    k_gemm_nt<1, false, false><<<dim3(8, 32), 256, 0, stream>>>(
        z_t, W_sz, nullptr, nullptr, b_sz, nullptr, r_t, 2048, 512, 512);
    // s_t = tanh(q_t @ W_sq.T + h_t @ W_sh.T + b_sq + b_sh)
    k_gemm_nt<1, true, false><<<dim3(8, 32), 256, 0, stream>>>(
        q_t, W_sq, h_t, W_sh, b_sq, b_sh, s_t, 2048, 512, 512);
    k_sentinel<<<1, 128, 0, stream>>>(s_t, r_t, Qh, W_Ss, b_Ss, W_Sr, b_Sr, W_bq, b_bq, epoch, gama);
    k_blend<<<2048, 256, 0, stream>>>(s_t, r_t, gama, c_t);
    // scores = c_t @ W_mlp.T + b_mlp
    k_gemm_nt<0, false, true><<<dim3(469, 32), 256, 0, stream>>>(
        c_t, W_mlp, nullptr, nullptr, b_mlp, nullptr, out, 2048, 30000, 512);
}

// Round 2
// 709.408 us; speedup vs baseline: 1.8351x; 1.8351x over previous
//
#include <hip/hip_runtime.h>
#include <hip/hip_bf16.h>

// Shapes: EMBED=HIDDEN=512, VOCAB=30000, B=16, S=128, K=49, NT=5, rows BS=2048

// ---------------------------------------------------------------------------
// K1: Zh = h_t @ W_Zh.T + b_Zh   (2048,49)  ; Qh = h_t @ W_Qh.T + b_Qh (2048,5)
__global__ void k_lin_h(const float* __restrict__ h,
                        const float* __restrict__ W_Zh, const float* __restrict__ b_Zh,
                        const float* __restrict__ W_Qh, const float* __restrict__ b_Qh,
                        float* __restrict__ Zh, float* __restrict__ Qh)
{
    __shared__ float hs[512];
    const int row = blockIdx.x;
    const float* hp = h + row * 512;
    for (int i = threadIdx.x; i < 512; i += 256) hs[i] = hp[i];
    __syncthreads();
    const int t = threadIdx.x;
    if (t < 49) {
        const float* w = W_Zh + t * 512;
        float acc = b_Zh[t];
        #pragma unroll 8
        for (int i = 0; i < 512; ++i) acc = fmaf(hs[i], w[i], acc);
        Zh[row * 64 + t] = acc;
    } else if (t >= 64 && t < 69) {
        const int o = t - 64;
        const float* w = W_Qh + o * 512;
        float acc = b_Qh[o];
        #pragma unroll 8
        for (int i = 0; i < 512; ++i) acc = fmaf(hs[i], w[i], acc);
        Qh[row * 8 + o] = acc;
    }
}

// ---------------------------------------------------------------------------
// K2: ZV = V @ W_ZV.T + b_ZV  (16*49,49) ; QT = T @ W_QT.T + b_QT (16*5,5)
__global__ void k_lin_vt(const float* __restrict__ V,
                         const float* __restrict__ W_ZV, const float* __restrict__ b_ZV,
                         const float* __restrict__ T,
                         const float* __restrict__ W_QT, const float* __restrict__ b_QT,
                         float* __restrict__ ZV, float* __restrict__ QT)
{
    __shared__ float xs[512];
    const int blk = blockIdx.x;
    const int t = threadIdx.x;
    if (blk < 784) {                      // V rows: b*49+k
        const float* xp = V + (size_t)blk * 512;
        for (int i = t; i < 512; i += 256) xs[i] = xp[i];
        __syncthreads();
        if (t < 49) {
            const float* w = W_ZV + t * 512;
            float acc = b_ZV[t];
            #pragma unroll 8
            for (int i = 0; i < 512; ++i) acc = fmaf(xs[i], w[i], acc);
            ZV[blk * 64 + t] = acc;
        }
    } else {                              // T rows: b*5+nt
        const int row = blk - 784;
        const float* xp = T + (size_t)row * 512;
        for (int i = t; i < 512; i += 256) xs[i] = xp[i];
        __syncthreads();
        if (t < 5) {
            const float* w = W_QT + t * 512;
            float acc = b_QT[t];
            #pragma unroll 8
            for (int i = 0; i < 512; ++i) acc = fmaf(xs[i], w[i], acc);
            QT[row * 8 + t] = acc;
        }
    }
}

// ---------------------------------------------------------------------------
// K3: per (b,s): visual + topic attention -> z_t (2048,512), q_t (2048,512)
__global__ void k_attn(const float* __restrict__ V, const float* __restrict__ T,
                       const float* __restrict__ ZV, const float* __restrict__ Zh,
                       const float* __restrict__ QT, const float* __restrict__ Qh,
                       const float* __restrict__ W_az, const float* __restrict__ b_az,
                       const float* __restrict__ W_bq, const float* __restrict__ b_bq,
                       float* __restrict__ z_t, float* __restrict__ q_t)
{
    const int row = blockIdx.x;       // b*128+s
    const int b = row >> 7;
    const int t = threadIdx.x;
    __shared__ float zh[49], waz[49], alpha[49], beta[5];
    if (t < 49) { zh[t] = Zh[row * 64 + t]; waz[t] = W_az[t]; }
    __syncthreads();
    if (t < 49) {
        const float* zv = ZV + (b * 49 + t) * 64;
        float acc = b_az[0];
        for (int j = 0; j < 49; ++j) acc += tanhf(zv[j] + zh[j]) * waz[j];
        alpha[t] = acc;
    } else if (t >= 64 && t < 69) {
        const int tt = t - 64;
        const float* qt = QT + (b * 5 + tt) * 8;
        const float* qh = Qh + row * 8;
        float acc = b_bq[0];
        for (int j = 0; j < 5; ++j) acc += tanhf(qt[j] + qh[j]) * W_bq[j];
        beta[tt] = acc;
    }
    __syncthreads();
    if (t == 0) {
        float m = -1e30f;
        for (int k = 0; k < 49; ++k) m = fmaxf(m, alpha[k]);
        float s = 0.f;
        for (int k = 0; k < 49; ++k) { alpha[k] = expf(alpha[k] - m); s += alpha[k]; }
        float inv = 1.f / s;
        for (int k = 0; k < 49; ++k) alpha[k] *= inv;
    } else if (t == 64) {
        float m = -1e30f;
        for (int k = 0; k < 5; ++k) m = fmaxf(m, beta[k]);
        float s = 0.f;
        for (int k = 0; k < 5; ++k) { beta[k] = expf(beta[k] - m); s += beta[k]; }
        float inv = 1.f / s;
        for (int k = 0; k < 5; ++k) beta[k] *= inv;
    }
    __syncthreads();
    const float* Vb = V + (size_t)b * 49 * 512;
    const float* Tb = T + (size_t)b * 5 * 512;
    for (int hd = t; hd < 512; hd += 256) {
        float az = 0.f;
        #pragma unroll
        for (int k = 0; k < 49; ++k) az = fmaf(alpha[k], Vb[k * 512 + hd], az);
        z_t[(size_t)row * 512 + hd] = az;
        float aq = 0.f;
        #pragma unroll
        for (int k = 0; k < 5; ++k) aq = fmaf(beta[k], Tb[k * 512 + hd], aq);
        q_t[(size_t)row * 512 + hd] = aq;
    }
}

// ---------------------------------------------------------------------------
// Tiled fp32 GEMM for the two 512x512 linears:
//   C[M,N] = act( A@W.T (+ A2@W2.T) + bias (+ bias2) )
template<int ACT, bool DUAL>
__global__ __launch_bounds__(256) void k_gemm_nt(
    const float* __restrict__ A, const float* __restrict__ W,
    const float* __restrict__ A2, const float* __restrict__ W2,
    const float* __restrict__ bias, const float* __restrict__ bias2,
    float* __restrict__ C, int M, int N, int K)
{
    __shared__ __align__(16) float As[32][68];
    __shared__ __align__(16) float Ws[32][68];
    const int tid = threadIdx.x;
    const int tx = tid & 15, ty = tid >> 4;
    const int m0 = blockIdx.y * 64, n0 = blockIdx.x * 64;
    float acc[4][4] = {};
    const int npass = DUAL ? 2 : 1;
    for (int pass = 0; pass < npass; ++pass) {
        const float* Ap = (DUAL && pass) ? A2 : A;
        const float* Wp = (DUAL && pass) ? W2 : W;
        for (int k0 = 0; k0 < K; k0 += 32) {
            #pragma unroll
            for (int e = 0; e < 8; ++e) {
                const int idx = tid + e * 256;
                const int r = idx >> 5, c = idx & 31;
                As[c][r] = Ap[(size_t)(m0 + r) * K + k0 + c];
                Ws[c][r] = Wp[(size_t)(n0 + r) * K + k0 + c];
            }
            __syncthreads();
            #pragma unroll
            for (int kk = 0; kk < 32; ++kk) {
                const float4 av = *(const float4*)(&As[kk][ty << 2]);
                const float4 wv = *(const float4*)(&Ws[kk][tx << 2]);
                const float a[4] = {av.x, av.y, av.z, av.w};
                const float w[4] = {wv.x, wv.y, wv.z, wv.w};
                #pragma unroll
                for (int i = 0; i < 4; ++i)
                    #pragma unroll
                    for (int j = 0; j < 4; ++j)
                        acc[i][j] = fmaf(a[i], w[j], acc[i][j]);
            }
            __syncthreads();
        }
    }
    #pragma unroll
    for (int i = 0; i < 4; ++i) {
        const int m = m0 + (ty << 2) + i;
        #pragma unroll
        for (int j = 0; j < 4; ++j) {
            const int n = n0 + (tx << 2) + j;
            float v = acc[i][j] + bias[n];
            if (DUAL) v += bias2[n];
            if (ACT == 1) v = tanhf(v);
            C[(size_t)m * N + n] = v;
        }
    }
}

// ---------------------------------------------------------------------------
// MLP GEMM, bf16 MFMA: out[2048,30000] = c_t[2048,512] @ W_mlp[30000,512].T + b
// 128x128 tile, BK=64, 4 waves, 16x16x32 MFMA, reg-staged fp32->bf16,
// XOR-swizzled LDS (chunk ^= row&7 on 16B chunks of a 128B row).
typedef short bf16x8 __attribute__((ext_vector_type(8)));
typedef float f32x4 __attribute__((ext_vector_type(4)));

static __device__ __forceinline__ short f2bf(float f) {
    union { float f; unsigned u; } v; v.f = f;
    unsigned r = v.u + 0x7FFFu + ((v.u >> 16) & 1u);   // RNE
    return (short)(r >> 16);
}

__global__ __launch_bounds__(256) void k_gemm_mfma(
    const float* __restrict__ A, const float* __restrict__ W,
    const float* __restrict__ bias, float* __restrict__ C)
{
    constexpr int N = 30000, K = 512;
    __shared__ __align__(16) short As[128 * 64];
    __shared__ __align__(16) short Ws[128 * 64];
    const int tid = threadIdx.x;
    const int l = tid & 63, w = tid >> 6;
    const int m0 = blockIdx.x * 128;          // m fast -> W panel L2 reuse
    const int n0 = blockIdx.y * 128;
    const int wm = (w & 1) * 64, wn = (w >> 1) * 64;
    const int r = tid >> 1, h = tid & 1;      // staging: row, k-half
    const bool wvalid = (n0 + r) < N;
    const float* Ap = A + (size_t)(m0 + r) * K + h * 32;
    const float* Wp = W + (size_t)(n0 + r) * K + h * 32;

    f32x4 acc[4][4] = {};
    const int lm = l & 15, lg = l >> 4;

    for (int k0 = 0; k0 < K; k0 += 64) {
        float af[32], wf[32];
        #pragma unroll
        for (int c = 0; c < 8; ++c) {
            *(float4*)(af + c * 4) = *(const float4*)(Ap + k0 + c * 4);
            if (wvalid) *(float4*)(wf + c * 4) = *(const float4*)(Wp + k0 + c * 4);
            else { wf[c*4] = 0.f; wf[c*4+1] = 0.f; wf[c*4+2] = 0.f; wf[c*4+3] = 0.f; }
        }
        __syncthreads();   // prev iteration's ds_reads complete
        #pragma unroll
        for (int c = 0; c < 4; ++c) {
            const int chunk = h * 4 + c;
            bf16x8 av, wv;
            #pragma unroll
            for (int j = 0; j < 8; ++j) {
                av[j] = f2bf(af[c * 8 + j]);
                wv[j] = f2bf(wf[c * 8 + j]);
            }
            const int sc = (chunk ^ (r & 7)) << 3;
            *(bf16x8*)(As + r * 64 + sc) = av;
            *(bf16x8*)(Ws + r * 64 + sc) = wv;
        }
        __syncthreads();   // LDS tile visible
        bf16x8 afr[2][4], bfr[2][4];
        #pragma unroll
        for (int s = 0; s < 2; ++s) {
            #pragma unroll
            for (int i = 0; i < 4; ++i) {
                const int ra = wm + i * 16 + lm;
                const int rb = wn + i * 16 + lm;
                const int ck = s * 4 + lg;
                afr[s][i] = *(const bf16x8*)(As + ra * 64 + ((ck ^ (ra & 7)) << 3));
                bfr[s][i] = *(const bf16x8*)(Ws + rb * 64 + ((ck ^ (rb & 7)) << 3));
            }
        }
        #pragma unroll
        for (int s = 0; s < 2; ++s)
            #pragma unroll
            for (int i = 0; i < 4; ++i)
                #pragma unroll
                for (int j = 0; j < 4; ++j)
                    acc[i][j] = __builtin_amdgcn_mfma_f32_16x16x32_bf16(
                        afr[s][i], bfr[s][j], acc[i][j], 0, 0, 0);
    }

    // epilogue: C/D layout col = l&15, row = (l>>4)*4 + reg
    #pragma unroll
    for (int j = 0; j < 4; ++j) {
        const int n = n0 + wn + j * 16 + lm;
        if (n >= N) continue;
        const float bj = bias[n];
        #pragma unroll
        for (int i = 0; i < 4; ++i) {
            const int m = m0 + wm + i * 16 + lg * 4;
            #pragma unroll
            for (int q = 0; q < 4; ++q)
                C[(size_t)(m + q) * N + n] = acc[i][j][q] + bj;
        }
    }
}

// ---------------------------------------------------------------------------
// K6: sentinel gate (batch 0 only, diagonal) -> gama[128]
__global__ void k_sentinel(const float* __restrict__ s_t, const float* __restrict__ r_t,
                           const float* __restrict__ Qh,
                           const float* __restrict__ W_Ss, const float* __restrict__ b_Ss,
                           const float* __restrict__ W_Sr, const float* __restrict__ b_Sr,
                           const float* __restrict__ W_bq, const float* __restrict__ b_bq,
                           const int* __restrict__ epoch, float* __restrict__ gama)
{
    const int s = threadIdx.x;   // 0..127
    if (epoch[0] <= 20) { gama[s] = 1.0f; return; }
    const float* sp = s_t + (size_t)s * 512;
    const float* rp = r_t + (size_t)s * 512;
    const float* qh = Qh + s * 8;
    float accs[5] = {}, accr[5] = {};
    for (int i = 0; i < 512; ++i) {
        const float sv = sp[i], rv = rp[i];
        #pragma unroll
        for (int t = 0; t < 5; ++t) {
            accs[t] = fmaf(sv, W_Ss[t * 512 + i], accs[t]);
            accr[t] = fmaf(rv, W_Sr[t * 512 + i], accr[t]);
        }
    }
    float ss = b_bq[0], sr = b_bq[0];
    #pragma unroll
    for (int t = 0; t < 5; ++t) {
        ss += tanhf(accs[t] + b_Ss[t] + qh[t]) * W_bq[t];
        sr += tanhf(accr[t] + b_Sr[t] + qh[t]) * W_bq[t];
    }
    gama[s] = 1.f / (1.f + expf(-(ss - sr)));
}

// ---------------------------------------------------------------------------
// K7: c_t = gama*s_t + (1-gama)*r_t
__global__ void k_blend(const float* __restrict__ s_t, const float* __restrict__ r_t,
                        const float* __restrict__ gama, float* __restrict__ c_t)
{
    const int row = blockIdx.x;
    const float g = gama[row & 127];
    const size_t base = (size_t)row * 512;
    for (int i = threadIdx.x; i < 512; i += 256)
        c_t[base + i] = g * s_t[base + i] + (1.f - g) * r_t[base + i];
}

// ---------------------------------------------------------------------------
extern "C" void kernel_launch(void* const* d_in, const int* in_sizes, int n_in,
                              void* d_out, int out_size, void* d_ws, size_t ws_size,
                              hipStream_t stream)
{
    const int*   epoch = (const int*)  d_in[0];
    const float* h_t   = (const float*)d_in[1];
    const float* V     = (const float*)d_in[2];
    const float* T     = (const float*)d_in[3];
    const float* W_ZV  = (const float*)d_in[4];  const float* b_ZV = (const float*)d_in[5];
    const float* W_Zh  = (const float*)d_in[6];  const float* b_Zh = (const float*)d_in[7];
    const float* W_az  = (const float*)d_in[8];  const float* b_az = (const float*)d_in[9];
    const float* W_QT  = (const float*)d_in[10]; const float* b_QT = (const float*)d_in[11];
    const float* W_Qh  = (const float*)d_in[12]; const float* b_Qh = (const float*)d_in[13];
    const float* W_bq  = (const float*)d_in[14]; const float* b_bq = (const float*)d_in[15];
    const float* W_sq  = (const float*)d_in[16]; const float* b_sq = (const float*)d_in[17];
    const float* W_sh  = (const float*)d_in[18]; const float* b_sh = (const float*)d_in[19];
    const float* W_Ss  = (const float*)d_in[20]; const float* b_Ss = (const float*)d_in[21];
    const float* W_Sr  = (const float*)d_in[22]; const float* b_Sr = (const float*)d_in[23];
    const float* W_sz  = (const float*)d_in[24]; const float* b_sz = (const float*)d_in[25];
    const float* W_mlp = (const float*)d_in[26]; const float* b_mlp= (const float*)d_in[27];

    float* out = (float*)d_out;
    float* ws  = (float*)d_ws;
    const size_t R = 2048 * 512;
    float* z_t  = ws;
    float* q_t  = ws + R;
    float* r_t  = ws + 2 * R;
    float* s_t  = ws + 3 * R;
    float* c_t  = ws + 4 * R;
    float* Zh   = ws + 5 * R;        // 2048*64
    float* ZV   = Zh + 2048 * 64;    // 784*64
    float* Qh   = ZV + 784 * 64;     // 2048*8
    float* QT   = Qh + 2048 * 8;     // 80*8
    float* gama = QT + 80 * 8;       // 128

    k_lin_h<<<2048, 256, 0, stream>>>(h_t, W_Zh, b_Zh, W_Qh, b_Qh, Zh, Qh);
    k_lin_vt<<<864, 256, 0, stream>>>(V, W_ZV, b_ZV, T, W_QT, b_QT, ZV, QT);
    k_attn<<<2048, 256, 0, stream>>>(V, T, ZV, Zh, QT, Qh, W_az, b_az, W_bq, b_bq, z_t, q_t);
    k_gemm_nt<1, false><<<dim3(8, 32), 256, 0, stream>>>(
        z_t, W_sz, nullptr, nullptr, b_sz, nullptr, r_t, 2048, 512, 512);
    k_gemm_nt<1, true><<<dim3(8, 32), 256, 0, stream>>>(
        q_t, W_sq, h_t, W_sh, b_sq, b_sh, s_t, 2048, 512, 512);
    k_sentinel<<<1, 128, 0, stream>>>(s_t, r_t, Qh, W_Ss, b_Ss, W_Sr, b_Sr, W_bq, b_bq, epoch, gama);
    k_blend<<<2048, 256, 0, stream>>>(s_t, r_t, gama, c_t);
    // scores = c_t @ W_mlp.T + b_mlp  (bf16 MFMA, m-fast grid for W reuse)
    k_gemm_mfma<<<dim3(16, 235), 256, 0, stream>>>(c_t, W_mlp, b_mlp, out);
}

// Round 3
// 378.304 us; speedup vs baseline: 3.4413x; 1.8752x over previous
//
#include <hip/hip_runtime.h>
#include <hip/hip_bf16.h>

// Shapes: EMBED=HIDDEN=512, VOCAB=30000, B=16, S=128, K=49, NT=5, rows BS=2048

typedef short bf16x8 __attribute__((ext_vector_type(8)));
typedef float f32x4 __attribute__((ext_vector_type(4)));
typedef short short8 __attribute__((ext_vector_type(8)));

static __device__ __forceinline__ short f2bf(float f) {
    union { float f; unsigned u; } v; v.f = f;
    unsigned r = v.u + 0x7FFFu + ((v.u >> 16) & 1u);   // RNE
    return (short)(r >> 16);
}

#define GLD_LDS16(gp, lp)                                                          \
    __builtin_amdgcn_global_load_lds(                                              \
        (const __attribute__((address_space(1))) unsigned int*)(gp),               \
        (__attribute__((address_space(3))) unsigned int*)(lp), 16, 0, 0)

// ---------------------------------------------------------------------------
// K0: fp32 -> bf16 bulk convert (for W_mlp), 8 elems/thread
__global__ __launch_bounds__(256) void k_cvt(const float* __restrict__ src,
                                             short* __restrict__ dst, int n8)
{
    const int i = blockIdx.x * 256 + threadIdx.x;
    if (i >= n8) return;
    const float4 a = ((const float4*)src)[i * 2];
    const float4 b = ((const float4*)src)[i * 2 + 1];
    short8 o;
    o[0] = f2bf(a.x); o[1] = f2bf(a.y); o[2] = f2bf(a.z); o[3] = f2bf(a.w);
    o[4] = f2bf(b.x); o[5] = f2bf(b.y); o[6] = f2bf(b.z); o[7] = f2bf(b.w);
    ((short8*)dst)[i] = o;
}

// ---------------------------------------------------------------------------
// K1: Zh = h_t @ W_Zh.T + b_Zh   (2048,49)  ; Qh = h_t @ W_Qh.T + b_Qh (2048,5)
__global__ void k_lin_h(const float* __restrict__ h,
                        const float* __restrict__ W_Zh, const float* __restrict__ b_Zh,
                        const float* __restrict__ W_Qh, const float* __restrict__ b_Qh,
                        float* __restrict__ Zh, float* __restrict__ Qh)
{
    __shared__ float hs[512];
    const int row = blockIdx.x;
    const float* hp = h + row * 512;
    for (int i = threadIdx.x; i < 512; i += 256) hs[i] = hp[i];
    __syncthreads();
    const int t = threadIdx.x;
    if (t < 49) {
        const float* w = W_Zh + t * 512;
        float acc = b_Zh[t];
        #pragma unroll 8
        for (int i = 0; i < 512; ++i) acc = fmaf(hs[i], w[i], acc);
        Zh[row * 64 + t] = acc;
    } else if (t >= 64 && t < 69) {
        const int o = t - 64;
        const float* w = W_Qh + o * 512;
        float acc = b_Qh[o];
        #pragma unroll 8
        for (int i = 0; i < 512; ++i) acc = fmaf(hs[i], w[i], acc);
        Qh[row * 8 + o] = acc;
    }
}

// ---------------------------------------------------------------------------
// K2: ZV = V @ W_ZV.T + b_ZV  (16*49,49) ; QT = T @ W_QT.T + b_QT (16*5,5)
__global__ void k_lin_vt(const float* __restrict__ V,
                         const float* __restrict__ W_ZV, const float* __restrict__ b_ZV,
                         const float* __restrict__ T,
                         const float* __restrict__ W_QT, const float* __restrict__ b_QT,
                         float* __restrict__ ZV, float* __restrict__ QT)
{
    __shared__ float xs[512];
    const int blk = blockIdx.x;
    const int t = threadIdx.x;
    if (blk < 784) {
        const float* xp = V + (size_t)blk * 512;
        for (int i = t; i < 512; i += 256) xs[i] = xp[i];
        __syncthreads();
        if (t < 49) {
            const float* w = W_ZV + t * 512;
            float acc = b_ZV[t];
            #pragma unroll 8
            for (int i = 0; i < 512; ++i) acc = fmaf(xs[i], w[i], acc);
            ZV[blk * 64 + t] = acc;
        }
    } else {
        const int row = blk - 784;
        const float* xp = T + (size_t)row * 512;
        for (int i = t; i < 512; i += 256) xs[i] = xp[i];
        __syncthreads();
        if (t < 5) {
            const float* w = W_QT + t * 512;
            float acc = b_QT[t];
            #pragma unroll 8
            for (int i = 0; i < 512; ++i) acc = fmaf(xs[i], w[i], acc);
            QT[row * 8 + t] = acc;
        }
    }
}

// ---------------------------------------------------------------------------
// K3: per (b,s): visual + topic attention -> z_t (2048,512), q_t (2048,512)
__global__ void k_attn(const float* __restrict__ V, const float* __restrict__ T,
                       const float* __restrict__ ZV, const float* __restrict__ Zh,
                       const float* __restrict__ QT, const float* __restrict__ Qh,
                       const float* __restrict__ W_az, const float* __restrict__ b_az,
                       const float* __restrict__ W_bq, const float* __restrict__ b_bq,
                       float* __restrict__ z_t, float* __restrict__ q_t)
{
    const int row = blockIdx.x;       // b*128+s
    const int b = row >> 7;
    const int t = threadIdx.x;
    __shared__ float zh[49], waz[49], alpha[49], beta[5];
    if (t < 49) { zh[t] = Zh[row * 64 + t]; waz[t] = W_az[t]; }
    __syncthreads();
    if (t < 49) {
        const float* zv = ZV + (b * 49 + t) * 64;
        float acc = b_az[0];
        for (int j = 0; j < 49; ++j) acc += tanhf(zv[j] + zh[j]) * waz[j];
        alpha[t] = acc;
    } else if (t >= 64 && t < 69) {
        const int tt = t - 64;
        const float* qt = QT + (b * 5 + tt) * 8;
        const float* qh = Qh + row * 8;
        float acc = b_bq[0];
        for (int j = 0; j < 5; ++j) acc += tanhf(qt[j] + qh[j]) * W_bq[j];
        beta[tt] = acc;
    }
    __syncthreads();
    if (t == 0) {
        float m = -1e30f;
        for (int k = 0; k < 49; ++k) m = fmaxf(m, alpha[k]);
        float s = 0.f;
        for (int k = 0; k < 49; ++k) { alpha[k] = expf(alpha[k] - m); s += alpha[k]; }
        float inv = 1.f / s;
        for (int k = 0; k < 49; ++k) alpha[k] *= inv;
    } else if (t == 64) {
        float m = -1e30f;
        for (int k = 0; k < 5; ++k) m = fmaxf(m, beta[k]);
        float s = 0.f;
        for (int k = 0; k < 5; ++k) { beta[k] = expf(beta[k] - m); s += beta[k]; }
        float inv = 1.f / s;
        for (int k = 0; k < 5; ++k) beta[k] *= inv;
    }
    __syncthreads();
    const float* Vb = V + (size_t)b * 49 * 512;
    const float* Tb = T + (size_t)b * 5 * 512;
    for (int hd = t; hd < 512; hd += 256) {
        float az = 0.f;
        #pragma unroll
        for (int k = 0; k < 49; ++k) az = fmaf(alpha[k], Vb[k * 512 + hd], az);
        z_t[(size_t)row * 512 + hd] = az;
        float aq = 0.f;
        #pragma unroll
        for (int k = 0; k < 5; ++k) aq = fmaf(beta[k], Tb[k * 512 + hd], aq);
        q_t[(size_t)row * 512 + hd] = aq;
    }
}

// ---------------------------------------------------------------------------
// Tiled fp32 GEMM for the two 512x512 linears:
//   C[M,N] = act( A@W.T (+ A2@W2.T) + bias (+ bias2) )
template<int ACT, bool DUAL>
__global__ __launch_bounds__(256) void k_gemm_nt(
    const float* __restrict__ A, const float* __restrict__ W,
    const float* __restrict__ A2, const float* __restrict__ W2,
    const float* __restrict__ bias, const float* __restrict__ bias2,
    float* __restrict__ C, int M, int N, int K)
{
    __shared__ __align__(16) float As[32][68];
    __shared__ __align__(16) float Ws[32][68];
    const int tid = threadIdx.x;
    const int tx = tid & 15, ty = tid >> 4;
    const int m0 = blockIdx.y * 64, n0 = blockIdx.x * 64;
    float acc[4][4] = {};
    const int npass = DUAL ? 2 : 1;
    for (int pass = 0; pass < npass; ++pass) {
        const float* Ap = (DUAL && pass) ? A2 : A;
        const float* Wp = (DUAL && pass) ? W2 : W;
        for (int k0 = 0; k0 < K; k0 += 32) {
            #pragma unroll
            for (int e = 0; e < 8; ++e) {
                const int idx = tid + e * 256;
                const int r = idx >> 5, c = idx & 31;
                As[c][r] = Ap[(size_t)(m0 + r) * K + k0 + c];
                Ws[c][r] = Wp[(size_t)(n0 + r) * K + k0 + c];
            }
            __syncthreads();
            #pragma unroll
            for (int kk = 0; kk < 32; ++kk) {
                const float4 av = *(const float4*)(&As[kk][ty << 2]);
                const float4 wv = *(const float4*)(&Ws[kk][tx << 2]);
                const float a[4] = {av.x, av.y, av.z, av.w};
                const float w[4] = {wv.x, wv.y, wv.z, wv.w};
                #pragma unroll
                for (int i = 0; i < 4; ++i)
                    #pragma unroll
                    for (int j = 0; j < 4; ++j)
                        acc[i][j] = fmaf(a[i], w[j], acc[i][j]);
            }
            __syncthreads();
        }
    }
    #pragma unroll
    for (int i = 0; i < 4; ++i) {
        const int m = m0 + (ty << 2) + i;
        #pragma unroll
        for (int j = 0; j < 4; ++j) {
            const int n = n0 + (tx << 2) + j;
            float v = acc[i][j] + bias[n];
            if (DUAL) v += bias2[n];
            if (ACT == 1) v = tanhf(v);
            C[(size_t)m * N + n] = v;
        }
    }
}

// ---------------------------------------------------------------------------
// MLP GEMM (m97 structure): out[2048,30000] = c_bf @ W_bf.T + b
// A,W already bf16. 128x128 tile, BK=64, 4 waves, global_load_lds width-16,
// linear LDS, 2-barrier K-loop, 16x16x32 bf16 MFMA.
__global__ __launch_bounds__(256) void k_gemm_mfma(
    const short* __restrict__ A, const short* __restrict__ Wb,
    const float* __restrict__ bias, float* __restrict__ C)
{
    constexpr int N = 30000, K = 512;
    __shared__ __align__(16) short As[128 * 64];
    __shared__ __align__(16) short Ws[128 * 64];
    const int tid = threadIdx.x;
    const int l = tid & 63, w = tid >> 6;
    const int m0 = blockIdx.x * 128;          // m fast -> W panel L2 reuse
    const int n0 = blockIdx.y * 128;
    const int wm = (w & 1) * 64, wn = (w >> 1) * 64;
    const int lm = l & 15, lg = l >> 4;
    const int lr = l >> 3, lc = (l & 7) * 8;  // staging: sub-row, k-chunk (shorts)

    const short* Ag = A  + (size_t)m0 * K;
    const short* Wg = Wb + (size_t)n0 * K;

    f32x4 acc[4][4] = {};

    for (int k0 = 0; k0 < K; k0 += 64) {
        #pragma unroll
        for (int i = 0; i < 4; ++i) {
            const int row = w * 32 + i * 8;                       // wave-uniform
            GLD_LDS16(Ag + (size_t)(row + lr) * K + k0 + lc, As + row * 64);
            GLD_LDS16(Wg + (size_t)(row + lr) * K + k0 + lc, Ws + row * 64);
        }
        __syncthreads();
        bf16x8 afr[2][4], bfr[2][4];
        #pragma unroll
        for (int s = 0; s < 2; ++s) {
            #pragma unroll
            for (int i = 0; i < 4; ++i) {
                afr[s][i] = *(const bf16x8*)(As + (wm + i * 16 + lm) * 64 + (s * 4 + lg) * 8);
                bfr[s][i] = *(const bf16x8*)(Ws + (wn + i * 16 + lm) * 64 + (s * 4 + lg) * 8);
            }
        }
        #pragma unroll
        for (int s = 0; s < 2; ++s)
            #pragma unroll
            for (int i = 0; i < 4; ++i)
                #pragma unroll
                for (int j = 0; j < 4; ++j)
                    acc[i][j] = __builtin_amdgcn_mfma_f32_16x16x32_bf16(
                        afr[s][i], bfr[s][j], acc[i][j], 0, 0, 0);
        __syncthreads();
    }

    // epilogue: C/D layout col = l&15, row = (l>>4)*4 + reg
    #pragma unroll
    for (int j = 0; j < 4; ++j) {
        const int n = n0 + wn + j * 16 + lm;
        if (n >= N) continue;
        const float bj = bias[n];
        #pragma unroll
        for (int i = 0; i < 4; ++i) {
            const int m = m0 + wm + i * 16 + lg * 4;
            #pragma unroll
            for (int q = 0; q < 4; ++q)
                C[(size_t)(m + q) * N + n] = acc[i][j][q] + bj;
        }
    }
}

// ---------------------------------------------------------------------------
// K6: sentinel gate (batch 0 only, diagonal) -> gama[128]
__global__ void k_sentinel(const float* __restrict__ s_t, const float* __restrict__ r_t,
                           const float* __restrict__ Qh,
                           const float* __restrict__ W_Ss, const float* __restrict__ b_Ss,
                           const float* __restrict__ W_Sr, const float* __restrict__ b_Sr,
                           const float* __restrict__ W_bq, const float* __restrict__ b_bq,
                           const int* __restrict__ epoch, float* __restrict__ gama)
{
    const int s = threadIdx.x;   // 0..127
    if (epoch[0] <= 20) { gama[s] = 1.0f; return; }
    const float* sp = s_t + (size_t)s * 512;
    const float* rp = r_t + (size_t)s * 512;
    const float* qh = Qh + s * 8;
    float accs[5] = {}, accr[5] = {};
    for (int i = 0; i < 512; ++i) {
        const float sv = sp[i], rv = rp[i];
        #pragma unroll
        for (int t = 0; t < 5; ++t) {
            accs[t] = fmaf(sv, W_Ss[t * 512 + i], accs[t]);
            accr[t] = fmaf(rv, W_Sr[t * 512 + i], accr[t]);
        }
    }
    float ss = b_bq[0], sr = b_bq[0];
    #pragma unroll
    for (int t = 0; t < 5; ++t) {
        ss += tanhf(accs[t] + b_Ss[t] + qh[t]) * W_bq[t];
        sr += tanhf(accr[t] + b_Sr[t] + qh[t]) * W_bq[t];
    }
    gama[s] = 1.f / (1.f + expf(-(ss - sr)));
}

// ---------------------------------------------------------------------------
// K7: c_bf = bf16( gama*s_t + (1-gama)*r_t )
__global__ void k_blend(const float* __restrict__ s_t, const float* __restrict__ r_t,
                        const float* __restrict__ gama, short* __restrict__ c_bf)
{
    const int row = blockIdx.x;
    const float g = gama[row & 127];
    const size_t base = (size_t)row * 512;
    for (int i = threadIdx.x; i < 512; i += 256)
        c_bf[base + i] = f2bf(g * s_t[base + i] + (1.f - g) * r_t[base + i]);
}

// ---------------------------------------------------------------------------
extern "C" void kernel_launch(void* const* d_in, const int* in_sizes, int n_in,
                              void* d_out, int out_size, void* d_ws, size_t ws_size,
                              hipStream_t stream)
{
    const int*   epoch = (const int*)  d_in[0];
    const float* h_t   = (const float*)d_in[1];
    const float* V     = (const float*)d_in[2];
    const float* T     = (const float*)d_in[3];
    const float* W_ZV  = (const float*)d_in[4];  const float* b_ZV = (const float*)d_in[5];
    const float* W_Zh  = (const float*)d_in[6];  const float* b_Zh = (const float*)d_in[7];
    const float* W_az  = (const float*)d_in[8];  const float* b_az = (const float*)d_in[9];
    const float* W_QT  = (const float*)d_in[10]; const float* b_QT = (const float*)d_in[11];
    const float* W_Qh  = (const float*)d_in[12]; const float* b_Qh = (const float*)d_in[13];
    const float* W_bq  = (const float*)d_in[14]; const float* b_bq = (const float*)d_in[15];
    const float* W_sq  = (const float*)d_in[16]; const float* b_sq = (const float*)d_in[17];
    const float* W_sh  = (const float*)d_in[18]; const float* b_sh = (const float*)d_in[19];
    const float* W_Ss  = (const float*)d_in[20]; const float* b_Ss = (const float*)d_in[21];
    const float* W_Sr  = (const float*)d_in[22]; const float* b_Sr = (const float*)d_in[23];
    const float* W_sz  = (const float*)d_in[24]; const float* b_sz = (const float*)d_in[25];
    const float* W_mlp = (const float*)d_in[26]; const float* b_mlp= (const float*)d_in[27];

    float* out = (float*)d_out;
    float* ws  = (float*)d_ws;
    const size_t R = 2048 * 512;
    float* z_t  = ws;
    float* q_t  = ws + R;
    float* r_t  = ws + 2 * R;
    float* s_t  = ws + 3 * R;
    short* c_bf = (short*)(ws + 4 * R);   // 2048*512 bf16 (2 MB, inside 4 MB slot)
    float* Zh   = ws + 5 * R;             // 2048*64
    float* ZV   = Zh + 2048 * 64;         // 784*64
    float* Qh   = ZV + 784 * 64;          // 2048*8
    float* QT   = Qh + 2048 * 8;          // 80*8
    float* gama = QT + 80 * 8;            // 128
    short* W_bf = (short*)(gama + 128);   // 30080*512 bf16 (incl. 80-row pad)

    // W_mlp fp32 -> bf16 (15.36M elems, 8 per thread)
    k_cvt<<<7500, 256, 0, stream>>>(W_mlp, W_bf, 15360000 / 8);

    k_lin_h<<<2048, 256, 0, stream>>>(h_t, W_Zh, b_Zh, W_Qh, b_Qh, Zh, Qh);
    k_lin_vt<<<864, 256, 0, stream>>>(V, W_ZV, b_ZV, T, W_QT, b_QT, ZV, QT);
    k_attn<<<2048, 256, 0, stream>>>(V, T, ZV, Zh, QT, Qh, W_az, b_az, W_bq, b_bq, z_t, q_t);
    k_gemm_nt<1, false><<<dim3(8, 32), 256, 0, stream>>>(
        z_t, W_sz, nullptr, nullptr, b_sz, nullptr, r_t, 2048, 512, 512);
    k_gemm_nt<1, true><<<dim3(8, 32), 256, 0, stream>>>(
        q_t, W_sq, h_t, W_sh, b_sq, b_sh, s_t, 2048, 512, 512);
    k_sentinel<<<1, 128, 0, stream>>>(s_t, r_t, Qh, W_Ss, b_Ss, W_Sr, b_Sr, W_bq, b_bq, epoch, gama);
    k_blend<<<2048, 256, 0, stream>>>(s_t, r_t, gama, c_bf);
    // scores = c_bf @ W_bf.T + b_mlp  (bf16 MFMA, global_load_lds staging)
    k_gemm_mfma<<<dim3(16, 235), 256, 0, stream>>>(c_bf, W_bf, b_mlp, out);
}

// Round 4
// 255.646 us; speedup vs baseline: 5.0924x; 1.4798x over previous
//
#include <hip/hip_runtime.h>
#include <hip/hip_bf16.h>

// Shapes: EMBED=HIDDEN=512, VOCAB=30000, B=16, S=128, K=49, NT=5, rows BS=2048

typedef short bf16x8 __attribute__((ext_vector_type(8)));
typedef float f32x4 __attribute__((ext_vector_type(4)));
typedef short short8 __attribute__((ext_vector_type(8)));

static __device__ __forceinline__ short f2bf(float f) {
    union { float f; unsigned u; } v; v.f = f;
    unsigned r = v.u + 0x7FFFu + ((v.u >> 16) & 1u);   // RNE
    return (short)(r >> 16);
}

#define GLD_LDS16(gp, lp)                                                          \
    __builtin_amdgcn_global_load_lds(                                              \
        (const __attribute__((address_space(1))) unsigned int*)(gp),               \
        (__attribute__((address_space(3))) unsigned int*)(lp), 16, 0, 0)

// ---------------------------------------------------------------------------
// K0: fp32 -> bf16 bulk convert: W_mlp (7500 blk), h_t (512), W_sz/W_sq/W_sh (128 ea)
__global__ __launch_bounds__(256) void k_cvt_all(
    const float* __restrict__ wmlp, short* __restrict__ wmlp_b,
    const float* __restrict__ h,    short* __restrict__ h_b,
    const float* __restrict__ wsz,  short* __restrict__ wsz_b,
    const float* __restrict__ wsq,  short* __restrict__ wsq_b,
    const float* __restrict__ wsh,  short* __restrict__ wsh_b)
{
    const int bid = blockIdx.x;
    const float* src; short* dst; int i;
    if (bid < 7500)      { src = wmlp; dst = wmlp_b; i = bid * 256 + threadIdx.x; }
    else if (bid < 8012) { src = h;    dst = h_b;    i = (bid - 7500) * 256 + threadIdx.x; }
    else if (bid < 8140) { src = wsz;  dst = wsz_b;  i = (bid - 8012) * 256 + threadIdx.x; }
    else if (bid < 8268) { src = wsq;  dst = wsq_b;  i = (bid - 8140) * 256 + threadIdx.x; }
    else                 { src = wsh;  dst = wsh_b;  i = (bid - 8268) * 256 + threadIdx.x; }
    const float4 a = ((const float4*)src)[i * 2];
    const float4 b = ((const float4*)src)[i * 2 + 1];
    short8 o;
    o[0] = f2bf(a.x); o[1] = f2bf(a.y); o[2] = f2bf(a.z); o[3] = f2bf(a.w);
    o[4] = f2bf(b.x); o[5] = f2bf(b.y); o[6] = f2bf(b.z); o[7] = f2bf(b.w);
    ((short8*)dst)[i] = o;
}

// ---------------------------------------------------------------------------
// K1: Zh = h_t @ W_Zh.T + b_Zh   (2048,49)  ; Qh = h_t @ W_Qh.T + b_Qh (2048,5)
__global__ void k_lin_h(const float* __restrict__ h,
                        const float* __restrict__ W_Zh, const float* __restrict__ b_Zh,
                        const float* __restrict__ W_Qh, const float* __restrict__ b_Qh,
                        float* __restrict__ Zh, float* __restrict__ Qh)
{
    __shared__ float hs[512];
    const int row = blockIdx.x;
    const float* hp = h + row * 512;
    for (int i = threadIdx.x; i < 512; i += 256) hs[i] = hp[i];
    __syncthreads();
    const int t = threadIdx.x;
    if (t < 49) {
        const float* w = W_Zh + t * 512;
        float acc = b_Zh[t];
        #pragma unroll 8
        for (int i = 0; i < 512; ++i) acc = fmaf(hs[i], w[i], acc);
        Zh[row * 64 + t] = acc;
    } else if (t >= 64 && t < 69) {
        const int o = t - 64;
        const float* w = W_Qh + o * 512;
        float acc = b_Qh[o];
        #pragma unroll 8
        for (int i = 0; i < 512; ++i) acc = fmaf(hs[i], w[i], acc);
        Qh[row * 8 + o] = acc;
    }
}

// ---------------------------------------------------------------------------
// K2: ZV = V @ W_ZV.T + b_ZV  (16*49,49) ; QT = T @ W_QT.T + b_QT (16*5,5)
__global__ void k_lin_vt(const float* __restrict__ V,
                         const float* __restrict__ W_ZV, const float* __restrict__ b_ZV,
                         const float* __restrict__ T,
                         const float* __restrict__ W_QT, const float* __restrict__ b_QT,
                         float* __restrict__ ZV, float* __restrict__ QT)
{
    __shared__ float xs[512];
    const int blk = blockIdx.x;
    const int t = threadIdx.x;
    if (blk < 784) {
        const float* xp = V + (size_t)blk * 512;
        for (int i = t; i < 512; i += 256) xs[i] = xp[i];
        __syncthreads();
        if (t < 49) {
            const float* w = W_ZV + t * 512;
            float acc = b_ZV[t];
            #pragma unroll 8
            for (int i = 0; i < 512; ++i) acc = fmaf(xs[i], w[i], acc);
            ZV[blk * 64 + t] = acc;
        }
    } else {
        const int row = blk - 784;
        const float* xp = T + (size_t)row * 512;
        for (int i = t; i < 512; i += 256) xs[i] = xp[i];
        __syncthreads();
        if (t < 5) {
            const float* w = W_QT + t * 512;
            float acc = b_QT[t];
            #pragma unroll 8
            for (int i = 0; i < 512; ++i) acc = fmaf(xs[i], w[i], acc);
            QT[row * 8 + t] = acc;
        }
    }
}

// ---------------------------------------------------------------------------
// K3: per (b,s): visual + topic attention -> z_bf (2048,512), q_bf (2048,512) bf16
__global__ void k_attn(const float* __restrict__ V, const float* __restrict__ T,
                       const float* __restrict__ ZV, const float* __restrict__ Zh,
                       const float* __restrict__ QT, const float* __restrict__ Qh,
                       const float* __restrict__ W_az, const float* __restrict__ b_az,
                       const float* __restrict__ W_bq, const float* __restrict__ b_bq,
                       short* __restrict__ z_bf, short* __restrict__ q_bf)
{
    const int row = blockIdx.x;       // b*128+s
    const int b = row >> 7;
    const int t = threadIdx.x;
    __shared__ float zh[49], waz[49], alpha[49], beta[5];
    if (t < 49) { zh[t] = Zh[row * 64 + t]; waz[t] = W_az[t]; }
    __syncthreads();
    if (t < 49) {
        const float* zv = ZV + (b * 49 + t) * 64;
        float acc = b_az[0];
        for (int j = 0; j < 49; ++j) acc += tanhf(zv[j] + zh[j]) * waz[j];
        alpha[t] = acc;
    } else if (t >= 64 && t < 69) {
        const int tt = t - 64;
        const float* qt = QT + (b * 5 + tt) * 8;
        const float* qh = Qh + row * 8;
        float acc = b_bq[0];
        for (int j = 0; j < 5; ++j) acc += tanhf(qt[j] + qh[j]) * W_bq[j];
        beta[tt] = acc;
    }
    __syncthreads();
    if (t == 0) {
        float m = -1e30f;
        for (int k = 0; k < 49; ++k) m = fmaxf(m, alpha[k]);
        float s = 0.f;
        for (int k = 0; k < 49; ++k) { alpha[k] = expf(alpha[k] - m); s += alpha[k]; }
        float inv = 1.f / s;
        for (int k = 0; k < 49; ++k) alpha[k] *= inv;
    } else if (t == 64) {
        float m = -1e30f;
        for (int k = 0; k < 5; ++k) m = fmaxf(m, beta[k]);
        float s = 0.f;
        for (int k = 0; k < 5; ++k) { beta[k] = expf(beta[k] - m); s += beta[k]; }
        float inv = 1.f / s;
        for (int k = 0; k < 5; ++k) beta[k] *= inv;
    }
    __syncthreads();
    const float* Vb = V + (size_t)b * 49 * 512;
    const float* Tb = T + (size_t)b * 5 * 512;
    for (int hd = t; hd < 512; hd += 256) {
        float az = 0.f;
        #pragma unroll
        for (int k = 0; k < 49; ++k) az = fmaf(alpha[k], Vb[k * 512 + hd], az);
        z_bf[(size_t)row * 512 + hd] = f2bf(az);
        float aq = 0.f;
        #pragma unroll
        for (int k = 0; k < 5; ++k) aq = fmaf(beta[k], Tb[k * 512 + hd], aq);
        q_bf[(size_t)row * 512 + hd] = f2bf(aq);
    }
}

// ---------------------------------------------------------------------------
// K4: r_t = tanh(z@Wsz.T + b_sz), s_t = tanh(q@Wsq.T + h@Wsh.T + b_sq + b_sh)
// bf16 MFMA, 64x64 tile, BK=64, 4 waves (each 32x32), 3 passes, grid (32,8).
__global__ __launch_bounds__(256) void k_rs(
    const short* __restrict__ Zb, const short* __restrict__ Qb, const short* __restrict__ Hb,
    const short* __restrict__ Wsz, const short* __restrict__ Wsq, const short* __restrict__ Wsh,
    const float* __restrict__ b_sz, const float* __restrict__ b_sq, const float* __restrict__ b_sh,
    float* __restrict__ r_t, float* __restrict__ s_t)
{
    constexpr int K = 512, NN = 512;
    __shared__ __align__(16) short sA[64 * 64];
    __shared__ __align__(16) short sW[64 * 64];
    const int tid = threadIdx.x;
    const int l = tid & 63, w = tid >> 6;
    const int m0 = blockIdx.x * 64, n0 = blockIdx.y * 64;
    const int wm = (w & 1) * 32, wn = (w >> 1) * 32;
    const int lm = l & 15, lg = l >> 4;
    const int sr = l >> 3, sc = l & 7;
    f32x4 accr[2][2] = {}, accs[2][2] = {};

#define RS_PASS(AG, WG, ACC)                                                      \
    for (int k0 = 0; k0 < K; k0 += 64) {                                          \
        _Pragma("unroll")                                                         \
        for (int c = 0; c < 2; ++c) {                                             \
            const int R = w * 16 + c * 8;                                         \
            const int row = R + sr;                                               \
            GLD_LDS16((AG) + (size_t)(m0 + row) * K + k0 + ((sc ^ (row & 7)) << 3), sA + R * 64); \
            GLD_LDS16((WG) + (size_t)(n0 + row) * K + k0 + ((sc ^ (row & 7)) << 3), sW + R * 64); \
        }                                                                         \
        __syncthreads();                                                          \
        bf16x8 af[2][2], bv[2][2];                                                \
        _Pragma("unroll")                                                         \
        for (int s = 0; s < 2; ++s)                                               \
            _Pragma("unroll")                                                     \
            for (int i = 0; i < 2; ++i) {                                         \
                const int ra = wm + i * 16 + lm;                                  \
                const int rb = wn + i * 16 + lm;                                  \
                af[s][i] = *(const bf16x8*)(sA + ra * 64 + (((s * 4 + lg) ^ (ra & 7)) << 3)); \
                bv[s][i] = *(const bf16x8*)(sW + rb * 64 + (((s * 4 + lg) ^ (rb & 7)) << 3)); \
            }                                                                     \
        _Pragma("unroll")                                                         \
        for (int s = 0; s < 2; ++s)                                               \
            _Pragma("unroll")                                                     \
            for (int i = 0; i < 2; ++i)                                           \
                _Pragma("unroll")                                                 \
                for (int j = 0; j < 2; ++j)                                       \
                    ACC[i][j] = __builtin_amdgcn_mfma_f32_16x16x32_bf16(af[s][i], bv[s][j], ACC[i][j], 0, 0, 0); \
        __syncthreads();                                                          \
    }

    RS_PASS(Zb, Wsz, accr)
    RS_PASS(Qb, Wsq, accs)
    RS_PASS(Hb, Wsh, accs)
#undef RS_PASS

    #pragma unroll
    for (int j = 0; j < 2; ++j) {
        const int n = n0 + wn + j * 16 + lm;
        const float br = b_sz[n];
        const float bs = b_sq[n] + b_sh[n];
        #pragma unroll
        for (int i = 0; i < 2; ++i) {
            const int m = m0 + wm + i * 16 + lg * 4;
            #pragma unroll
            for (int q = 0; q < 4; ++q) {
                r_t[(size_t)(m + q) * NN + n] = tanhf(accr[i][j][q] + br);
                s_t[(size_t)(m + q) * NN + n] = tanhf(accs[i][j][q] + bs);
            }
        }
    }
}

// ---------------------------------------------------------------------------
// K5: MLP GEMM, deep-pipelined: out[2048,30000] = c_bf @ W_bf.T + b_mlp
// 128x128 tile, BK=32, double-buffered LDS, counted vmcnt(4), bare barriers,
// T2 source-pre-swizzle (chunk ^= (row>>1)&3).
__global__ __launch_bounds__(256) void k_gemm_mlp(
    const short* __restrict__ A, const short* __restrict__ Wb,
    const float* __restrict__ bias, float* __restrict__ C)
{
    constexpr int N = 30000, K = 512;
    __shared__ __align__(16) short shA[2][128 * 32];
    __shared__ __align__(16) short shW[2][128 * 32];
    const int tid = threadIdx.x;
    const int l = tid & 63, w = tid >> 6;
    const int m0 = blockIdx.x * 128;          // m fast -> W panel L2 reuse
    const int n0 = blockIdx.y * 128;
    const int wm = (w & 1) * 64, wn = (w >> 1) * 64;
    const int lm = l & 15, lg = l >> 4;
    const int sr = l >> 2, sc = l & 3;        // staging: row-in-call, 16B chunk
    const short* Ag = A  + (size_t)m0 * K;
    const short* Wg = Wb + (size_t)n0 * K;
    f32x4 acc[4][4] = {};

#define MLP_STAGE(b, t) {                                                         \
    const int kk = (t) * 32;                                                      \
    _Pragma("unroll")                                                             \
    for (int c = 0; c < 2; ++c) {                                                 \
        const int R = w * 32 + c * 16;                                            \
        const int row = R + sr;                                                   \
        GLD_LDS16(Ag + (size_t)row * K + kk + ((sc ^ ((row >> 1) & 3)) << 3),     \
                  shA[b] + R * 32);                                               \
        GLD_LDS16(Wg + (size_t)row * K + kk + ((sc ^ ((row >> 1) & 3)) << 3),     \
                  shW[b] + R * 32);                                               \
    } }

#define MLP_STEP(t, vmstr, dostage) {                                             \
    const int p = (t) & 1;                                                        \
    bf16x8 af[4], bv[4];                                                          \
    _Pragma("unroll")                                                             \
    for (int i = 0; i < 4; ++i) {                                                 \
        const int ra = wm + i * 16 + lm;                                          \
        const int rb = wn + i * 16 + lm;                                          \
        af[i] = *(const bf16x8*)(shA[p] + ra * 32 + ((lg ^ ((ra >> 1) & 3)) << 3)); \
        bv[i] = *(const bf16x8*)(shW[p] + rb * 32 + ((lg ^ ((rb >> 1) & 3)) << 3)); \
    }                                                                             \
    asm volatile("s_waitcnt lgkmcnt(0)" ::: "memory");                            \
    __builtin_amdgcn_s_barrier();                                                 \
    if (dostage) MLP_STAGE(p, (t) + 2);                                           \
    __builtin_amdgcn_sched_barrier(0);                                            \
    _Pragma("unroll")                                                             \
    for (int i = 0; i < 4; ++i)                                                   \
        _Pragma("unroll")                                                         \
        for (int j = 0; j < 4; ++j)                                               \
            acc[i][j] = __builtin_amdgcn_mfma_f32_16x16x32_bf16(af[i], bv[j], acc[i][j], 0, 0, 0); \
    asm volatile(vmstr ::: "memory");                                             \
    __builtin_amdgcn_s_barrier();                                                 \
  }

    MLP_STAGE(0, 0)
    MLP_STAGE(1, 1)
    asm volatile("s_waitcnt vmcnt(4)" ::: "memory");
    __builtin_amdgcn_s_barrier();

    MLP_STEP(0,  "s_waitcnt vmcnt(4)", 1)
    MLP_STEP(1,  "s_waitcnt vmcnt(4)", 1)
    MLP_STEP(2,  "s_waitcnt vmcnt(4)", 1)
    MLP_STEP(3,  "s_waitcnt vmcnt(4)", 1)
    MLP_STEP(4,  "s_waitcnt vmcnt(4)", 1)
    MLP_STEP(5,  "s_waitcnt vmcnt(4)", 1)
    MLP_STEP(6,  "s_waitcnt vmcnt(4)", 1)
    MLP_STEP(7,  "s_waitcnt vmcnt(4)", 1)
    MLP_STEP(8,  "s_waitcnt vmcnt(4)", 1)
    MLP_STEP(9,  "s_waitcnt vmcnt(4)", 1)
    MLP_STEP(10, "s_waitcnt vmcnt(4)", 1)
    MLP_STEP(11, "s_waitcnt vmcnt(4)", 1)
    MLP_STEP(12, "s_waitcnt vmcnt(4)", 1)
    MLP_STEP(13, "s_waitcnt vmcnt(4)", 1)
    MLP_STEP(14, "s_waitcnt vmcnt(0)", 0)
    MLP_STEP(15, "s_waitcnt vmcnt(0)", 0)
#undef MLP_STEP
#undef MLP_STAGE

    // epilogue: C/D layout col = l&15, row = (l>>4)*4 + reg
    #pragma unroll
    for (int j = 0; j < 4; ++j) {
        const int n = n0 + wn + j * 16 + lm;
        if (n >= N) continue;
        const float bj = bias[n];
        #pragma unroll
        for (int i = 0; i < 4; ++i) {
            const int m = m0 + wm + i * 16 + lg * 4;
            #pragma unroll
            for (int q = 0; q < 4; ++q)
                C[(size_t)(m + q) * N + n] = acc[i][j][q] + bj;
        }
    }
}

// ---------------------------------------------------------------------------
// K6: sentinel gate (batch 0, diagonal) -> gama[128]; 128 blocks x 64 lanes
__global__ void k_sentinel(const float* __restrict__ s_t, const float* __restrict__ r_t,
                           const float* __restrict__ Qh,
                           const float* __restrict__ W_Ss, const float* __restrict__ b_Ss,
                           const float* __restrict__ W_Sr, const float* __restrict__ b_Sr,
                           const float* __restrict__ W_bq, const float* __restrict__ b_bq,
                           const int* __restrict__ epoch, float* __restrict__ gama)
{
    const int s = blockIdx.x, l = threadIdx.x;
    if (epoch[0] <= 20) { if (l == 0) gama[s] = 1.0f; return; }
    const int d = l * 8;
    const float4 s0 = *(const float4*)(s_t + (size_t)s * 512 + d);
    const float4 s1 = *(const float4*)(s_t + (size_t)s * 512 + d + 4);
    const float4 r0 = *(const float4*)(r_t + (size_t)s * 512 + d);
    const float4 r1 = *(const float4*)(r_t + (size_t)s * 512 + d + 4);
    float ss = b_bq[0], sr = b_bq[0];
    #pragma unroll
    for (int t = 0; t < 5; ++t) {
        const float4 w0 = *(const float4*)(W_Ss + t * 512 + d);
        const float4 w1 = *(const float4*)(W_Ss + t * 512 + d + 4);
        const float4 v0 = *(const float4*)(W_Sr + t * 512 + d);
        const float4 v1 = *(const float4*)(W_Sr + t * 512 + d + 4);
        float as = s0.x*w0.x + s0.y*w0.y + s0.z*w0.z + s0.w*w0.w
                 + s1.x*w1.x + s1.y*w1.y + s1.z*w1.z + s1.w*w1.w;
        float ar = r0.x*v0.x + r0.y*v0.y + r0.z*v0.z + r0.w*v0.w
                 + r1.x*v1.x + r1.y*v1.y + r1.z*v1.z + r1.w*v1.w;
        #pragma unroll
        for (int off = 32; off; off >>= 1) {
            as += __shfl_xor(as, off);
            ar += __shfl_xor(ar, off);
        }
        const float qh = Qh[s * 8 + t];
        ss += tanhf(as + b_Ss[t] + qh) * W_bq[t];
        sr += tanhf(ar + b_Sr[t] + qh) * W_bq[t];
    }
    if (l == 0) gama[s] = 1.f / (1.f + expf(-(ss - sr)));
}

// ---------------------------------------------------------------------------
// K7: c_bf = bf16( gama*s_t + (1-gama)*r_t )
__global__ void k_blend(const float* __restrict__ s_t, const float* __restrict__ r_t,
                        const float* __restrict__ gama, short* __restrict__ c_bf)
{
    const int row = blockIdx.x;
    const float g = gama[row & 127];
    const size_t base = (size_t)row * 512;
    for (int i = threadIdx.x; i < 512; i += 256)
        c_bf[base + i] = f2bf(g * s_t[base + i] + (1.f - g) * r_t[base + i]);
}

// ---------------------------------------------------------------------------
extern "C" void kernel_launch(void* const* d_in, const int* in_sizes, int n_in,
                              void* d_out, int out_size, void* d_ws, size_t ws_size,
                              hipStream_t stream)
{
    const int*   epoch = (const int*)  d_in[0];
    const float* h_t   = (const float*)d_in[1];
    const float* V     = (const float*)d_in[2];
    const float* T     = (const float*)d_in[3];
    const float* W_ZV  = (const float*)d_in[4];  const float* b_ZV = (const float*)d_in[5];
    const float* W_Zh  = (const float*)d_in[6];  const float* b_Zh = (const float*)d_in[7];
    const float* W_az  = (const float*)d_in[8];  const float* b_az = (const float*)d_in[9];
    const float* W_QT  = (const float*)d_in[10]; const float* b_QT = (const float*)d_in[11];
    const float* W_Qh  = (const float*)d_in[12]; const float* b_Qh = (const float*)d_in[13];
    const float* W_bq  = (const float*)d_in[14]; const float* b_bq = (const float*)d_in[15];
    const float* W_sq  = (const float*)d_in[16]; const float* b_sq = (const float*)d_in[17];
    const float* W_sh  = (const float*)d_in[18]; const float* b_sh = (const float*)d_in[19];
    const float* W_Ss  = (const float*)d_in[20]; const float* b_Ss = (const float*)d_in[21];
    const float* W_Sr  = (const float*)d_in[22]; const float* b_Sr = (const float*)d_in[23];
    const float* W_sz  = (const float*)d_in[24]; const float* b_sz = (const float*)d_in[25];
    const float* W_mlp = (const float*)d_in[26]; const float* b_mlp= (const float*)d_in[27];

    float* out = (float*)d_out;
    float* ws  = (float*)d_ws;
    const size_t M1 = 1024 * 1024;        // 2048*512
    float* r_t  = ws;                     // 1M f
    float* s_t  = ws + M1;                // 1M f
    float* Zh   = ws + 2 * M1;            // 131072 f
    float* ZV   = Zh + 2048 * 64;         // 50176 f
    float* Qh   = ZV + 784 * 64;          // 16384 f
    float* QT   = Qh + 2048 * 8;          // 640 f
    float* gama = QT + 80 * 8;            // 128 f
    short* sreg = (short*)(gama + 128);
    short* z_bf   = sreg;                 // 1M sh
    short* q_bf   = z_bf + M1;            // 1M sh
    short* h_bf   = q_bf + M1;            // 1M sh
    short* c_bf   = h_bf + M1;            // 1M sh
    short* Wsz_bf = c_bf + M1;            // 256K sh
    short* Wsq_bf = Wsz_bf + 512 * 512;
    short* Wsh_bf = Wsq_bf + 512 * 512;
    short* W_bf   = Wsh_bf + 512 * 512;   // 30080*512 sh (incl. 80-row pad)

    k_cvt_all<<<8396, 256, 0, stream>>>(W_mlp, W_bf, h_t, h_bf,
                                        W_sz, Wsz_bf, W_sq, Wsq_bf, W_sh, Wsh_bf);
    k_lin_h<<<2048, 256, 0, stream>>>(h_t, W_Zh, b_Zh, W_Qh, b_Qh, Zh, Qh);
    k_lin_vt<<<864, 256, 0, stream>>>(V, W_ZV, b_ZV, T, W_QT, b_QT, ZV, QT);
    k_attn<<<2048, 256, 0, stream>>>(V, T, ZV, Zh, QT, Qh, W_az, b_az, W_bq, b_bq, z_bf, q_bf);
    k_rs<<<dim3(32, 8), 256, 0, stream>>>(z_bf, q_bf, h_bf, Wsz_bf, Wsq_bf, Wsh_bf,
                                          b_sz, b_sq, b_sh, r_t, s_t);
    k_sentinel<<<128, 64, 0, stream>>>(s_t, r_t, Qh, W_Ss, b_Ss, W_Sr, b_Sr, W_bq, b_bq, epoch, gama);
    k_blend<<<2048, 256, 0, stream>>>(s_t, r_t, gama, c_bf);
    k_gemm_mlp<<<dim3(16, 235), 256, 0, stream>>>(c_bf, W_bf, b_mlp, out);
}

// Round 5
// 217.278 us; speedup vs baseline: 5.9916x; 1.1766x over previous
//
#include <hip/hip_runtime.h>
#include <hip/hip_bf16.h>

// Shapes: EMBED=HIDDEN=512, VOCAB=30000, B=16, S=128, K=49, NT=5, rows BS=2048

typedef short bf16x8 __attribute__((ext_vector_type(8)));
typedef float f32x4 __attribute__((ext_vector_type(4)));
typedef short short8 __attribute__((ext_vector_type(8)));

static __device__ __forceinline__ short f2bf(float f) {
    union { float f; unsigned u; } v; v.f = f;
    unsigned r = v.u + 0x7FFFu + ((v.u >> 16) & 1u);   // RNE
    return (short)(r >> 16);
}

#define GLD_LDS16(gp, lp)                                                          \
    __builtin_amdgcn_global_load_lds(                                              \
        (const __attribute__((address_space(1))) unsigned int*)(gp),               \
        (__attribute__((address_space(3))) unsigned int*)(lp), 16, 0, 0)

// ---------------------------------------------------------------------------
// K_front: fused independent front work, critical-path blocks first.
//   [0,2048)        lin_h:  Zh = h@W_Zh.T+b, Qh = h@W_Qh.T+b
//   [2048,2912)     lin_vt: ZV = V@W_ZV.T+b, QT = T@W_QT.T+b
//   [2912,10412)    cvt W_mlp -> W_bf      (7500)
//   [10412,10924)   cvt h_t  -> h_bf       (512)
//   [10924,11052)   cvt W_sz -> Wsz_bf     (128)
//   [11052,11180)   cvt W_sq -> Wsq_bf     (128)
//   [11180,11308)   cvt W_sh -> Wsh_bf     (128)
__global__ __launch_bounds__(256) void k_front(
    const float* __restrict__ h, const float* __restrict__ V, const float* __restrict__ T,
    const float* __restrict__ W_Zh, const float* __restrict__ b_Zh,
    const float* __restrict__ W_Qh, const float* __restrict__ b_Qh,
    const float* __restrict__ W_ZV, const float* __restrict__ b_ZV,
    const float* __restrict__ W_QT, const float* __restrict__ b_QT,
    float* __restrict__ Zh, float* __restrict__ Qh,
    float* __restrict__ ZV, float* __restrict__ QT,
    const float* __restrict__ wmlp, short* __restrict__ wmlp_b,
    short* __restrict__ h_b,
    const float* __restrict__ wsz, short* __restrict__ wsz_b,
    const float* __restrict__ wsq, short* __restrict__ wsq_b,
    const float* __restrict__ wsh, short* __restrict__ wsh_b)
{
    __shared__ float xs[512];
    const int bid = blockIdx.x;
    const int t = threadIdx.x;

    if (bid < 2048) {                         // lin_h
        const float* hp = h + (size_t)bid * 512;
        for (int i = t; i < 512; i += 256) xs[i] = hp[i];
        __syncthreads();
        if (t < 49) {
            const float* w = W_Zh + t * 512;
            float acc = b_Zh[t];
            #pragma unroll 8
            for (int i = 0; i < 512; ++i) acc = fmaf(xs[i], w[i], acc);
            Zh[bid * 64 + t] = acc;
        } else if (t >= 64 && t < 69) {
            const int o = t - 64;
            const float* w = W_Qh + o * 512;
            float acc = b_Qh[o];
            #pragma unroll 8
            for (int i = 0; i < 512; ++i) acc = fmaf(xs[i], w[i], acc);
            Qh[bid * 8 + o] = acc;
        }
        return;
    }
    if (bid < 2912) {                         // lin_vt
        const int blk = bid - 2048;
        if (blk < 784) {
            const float* xp = V + (size_t)blk * 512;
            for (int i = t; i < 512; i += 256) xs[i] = xp[i];
            __syncthreads();
            if (t < 49) {
                const float* w = W_ZV + t * 512;
                float acc = b_ZV[t];
                #pragma unroll 8
                for (int i = 0; i < 512; ++i) acc = fmaf(xs[i], w[i], acc);
                ZV[blk * 64 + t] = acc;
            }
        } else {
            const int row = blk - 784;
            const float* xp = T + (size_t)row * 512;
            for (int i = t; i < 512; i += 256) xs[i] = xp[i];
            __syncthreads();
            if (t < 5) {
                const float* w = W_QT + t * 512;
                float acc = b_QT[t];
                #pragma unroll 8
                for (int i = 0; i < 512; ++i) acc = fmaf(xs[i], w[i], acc);
                QT[row * 8 + t] = acc;
            }
        }
        return;
    }
    // cvt sections
    const float* src; short* dst; int i;
    if (bid < 10412)      { src = wmlp; dst = wmlp_b; i = (bid - 2912) * 256 + t; }
    else if (bid < 10924) { src = h;    dst = h_b;    i = (bid - 10412) * 256 + t; }
    else if (bid < 11052) { src = wsz;  dst = wsz_b;  i = (bid - 10924) * 256 + t; }
    else if (bid < 11180) { src = wsq;  dst = wsq_b;  i = (bid - 11052) * 256 + t; }
    else                  { src = wsh;  dst = wsh_b;  i = (bid - 11180) * 256 + t; }
    const float4 a = ((const float4*)src)[i * 2];
    const float4 b = ((const float4*)src)[i * 2 + 1];
    short8 o;
    o[0] = f2bf(a.x); o[1] = f2bf(a.y); o[2] = f2bf(a.z); o[3] = f2bf(a.w);
    o[4] = f2bf(b.x); o[5] = f2bf(b.y); o[6] = f2bf(b.z); o[7] = f2bf(b.w);
    ((short8*)dst)[i] = o;
}

// ---------------------------------------------------------------------------
// K3: per (b,s): visual + topic attention -> z_bf, q_bf (2048,512) bf16
__global__ void k_attn(const float* __restrict__ V, const float* __restrict__ T,
                       const float* __restrict__ ZV, const float* __restrict__ Zh,
                       const float* __restrict__ QT, const float* __restrict__ Qh,
                       const float* __restrict__ W_az, const float* __restrict__ b_az,
                       const float* __restrict__ W_bq, const float* __restrict__ b_bq,
                       short* __restrict__ z_bf, short* __restrict__ q_bf)
{
    const int row = blockIdx.x;       // b*128+s
    const int b = row >> 7;
    const int t = threadIdx.x;
    __shared__ float zh[49], waz[49], alpha[49], beta[5];
    if (t < 49) { zh[t] = Zh[row * 64 + t]; waz[t] = W_az[t]; }
    __syncthreads();
    if (t < 49) {
        const float* zv = ZV + (b * 49 + t) * 64;
        float acc = b_az[0];
        for (int j = 0; j < 49; ++j) acc += tanhf(zv[j] + zh[j]) * waz[j];
        alpha[t] = acc;
    } else if (t >= 64 && t < 69) {
        const int tt = t - 64;
        const float* qt = QT + (b * 5 + tt) * 8;
        const float* qh = Qh + row * 8;
        float acc = b_bq[0];
        for (int j = 0; j < 5; ++j) acc += tanhf(qt[j] + qh[j]) * W_bq[j];
        beta[tt] = acc;
    }
    __syncthreads();
    if (t == 0) {
        float m = -1e30f;
        for (int k = 0; k < 49; ++k) m = fmaxf(m, alpha[k]);
        float s = 0.f;
        for (int k = 0; k < 49; ++k) { alpha[k] = expf(alpha[k] - m); s += alpha[k]; }
        float inv = 1.f / s;
        for (int k = 0; k < 49; ++k) alpha[k] *= inv;
    } else if (t == 64) {
        float m = -1e30f;
        for (int k = 0; k < 5; ++k) m = fmaxf(m, beta[k]);
        float s = 0.f;
        for (int k = 0; k < 5; ++k) { beta[k] = expf(beta[k] - m); s += beta[k]; }
        float inv = 1.f / s;
        for (int k = 0; k < 5; ++k) beta[k] *= inv;
    }
    __syncthreads();
    const float* Vb = V + (size_t)b * 49 * 512;
    const float* Tb = T + (size_t)b * 5 * 512;
    for (int hd = t; hd < 512; hd += 256) {
        float az = 0.f;
        #pragma unroll
        for (int k = 0; k < 49; ++k) az = fmaf(alpha[k], Vb[k * 512 + hd], az);
        z_bf[(size_t)row * 512 + hd] = f2bf(az);
        float aq = 0.f;
        #pragma unroll
        for (int k = 0; k < 5; ++k) aq = fmaf(beta[k], Tb[k * 512 + hd], aq);
        q_bf[(size_t)row * 512 + hd] = f2bf(aq);
    }
}

// ---------------------------------------------------------------------------
// K4: r_t = tanh(z@Wsz.T + b_sz), s_t = tanh(q@Wsq.T + h@Wsh.T + b_sq + b_sh)
__global__ __launch_bounds__(256) void k_rs(
    const short* __restrict__ Zb, const short* __restrict__ Qb, const short* __restrict__ Hb,
    const short* __restrict__ Wsz, const short* __restrict__ Wsq, const short* __restrict__ Wsh,
    const float* __restrict__ b_sz, const float* __restrict__ b_sq, const float* __restrict__ b_sh,
    float* __restrict__ r_t, float* __restrict__ s_t)
{
    constexpr int K = 512, NN = 512;
    __shared__ __align__(16) short sA[64 * 64];
    __shared__ __align__(16) short sW[64 * 64];
    const int tid = threadIdx.x;
    const int l = tid & 63, w = tid >> 6;
    const int m0 = blockIdx.x * 64, n0 = blockIdx.y * 64;
    const int wm = (w & 1) * 32, wn = (w >> 1) * 32;
    const int lm = l & 15, lg = l >> 4;
    const int sr = l >> 3, sc = l & 7;
    f32x4 accr[2][2] = {}, accs[2][2] = {};

#define RS_PASS(AG, WG, ACC)                                                      \
    for (int k0 = 0; k0 < K; k0 += 64) {                                          \
        _Pragma("unroll")                                                         \
        for (int c = 0; c < 2; ++c) {                                             \
            const int R = w * 16 + c * 8;                                         \
            const int row = R + sr;                                               \
            GLD_LDS16((AG) + (size_t)(m0 + row) * K + k0 + ((sc ^ (row & 7)) << 3), sA + R * 64); \
            GLD_LDS16((WG) + (size_t)(n0 + row) * K + k0 + ((sc ^ (row & 7)) << 3), sW + R * 64); \
        }                                                                         \
        __syncthreads();                                                          \
        bf16x8 af[2][2], bv[2][2];                                                \
        _Pragma("unroll")                                                         \
        for (int s = 0; s < 2; ++s)                                               \
            _Pragma("unroll")                                                     \
            for (int i = 0; i < 2; ++i) {                                         \
                const int ra = wm + i * 16 + lm;                                  \
                const int rb = wn + i * 16 + lm;                                  \
                af[s][i] = *(const bf16x8*)(sA + ra * 64 + (((s * 4 + lg) ^ (ra & 7)) << 3)); \
                bv[s][i] = *(const bf16x8*)(sW + rb * 64 + (((s * 4 + lg) ^ (rb & 7)) << 3)); \
            }                                                                     \
        _Pragma("unroll")                                                         \
        for (int s = 0; s < 2; ++s)                                               \
            _Pragma("unroll")                                                     \
            for (int i = 0; i < 2; ++i)                                           \
                _Pragma("unroll")                                                 \
                for (int j = 0; j < 2; ++j)                                       \
                    ACC[i][j] = __builtin_amdgcn_mfma_f32_16x16x32_bf16(af[s][i], bv[s][j], ACC[i][j], 0, 0, 0); \
        __syncthreads();                                                          \
    }

    RS_PASS(Zb, Wsz, accr)
    RS_PASS(Qb, Wsq, accs)
    RS_PASS(Hb, Wsh, accs)
#undef RS_PASS

    #pragma unroll
    for (int j = 0; j < 2; ++j) {
        const int n = n0 + wn + j * 16 + lm;
        const float br = b_sz[n];
        const float bs = b_sq[n] + b_sh[n];
        #pragma unroll
        for (int i = 0; i < 2; ++i) {
            const int m = m0 + wm + i * 16 + lg * 4;
            #pragma unroll
            for (int q = 0; q < 4; ++q) {
                r_t[(size_t)(m + q) * NN + n] = tanhf(accr[i][j][q] + br);
                s_t[(size_t)(m + q) * NN + n] = tanhf(accs[i][j][q] + bs);
            }
        }
    }
}

// ---------------------------------------------------------------------------
// K5: MLP GEMM, deep-pipelined + T1 XCD swizzle + nontemporal stores.
__global__ __launch_bounds__(256) void k_gemm_mlp(
    const short* __restrict__ A, const short* __restrict__ Wb,
    const float* __restrict__ bias, float* __restrict__ C)
{
    constexpr int N = 30000, K = 512;
    __shared__ __align__(16) short shA[2][128 * 32];
    __shared__ __align__(16) short shW[2][128 * 32];
    const int tid = threadIdx.x;
    const int l = tid & 63, w = tid >> 6;
    // XCD-chunked swizzle: 3760 blocks, 3760%8==0 -> bijective simple form.
    // XCD k owns contiguous swz range -> its 16-block m-chunks share W panels.
    const int bid = blockIdx.x;
    const int swz = (bid & 7) * 470 + (bid >> 3);
    const int m0 = (swz & 15) * 128;          // m fast -> W panel L2 reuse
    const int n0 = (swz >> 4) * 128;
    const int wm = (w & 1) * 64, wn = (w >> 1) * 64;
    const int lm = l & 15, lg = l >> 4;
    const int sr = l >> 2, sc = l & 3;        // staging: row-in-call, 16B chunk
    const short* Ag = A  + (size_t)m0 * K;
    const short* Wg = Wb + (size_t)n0 * K;
    f32x4 acc[4][4] = {};

#define MLP_STAGE(b, t) {                                                         \
    const int kk = (t) * 32;                                                      \
    _Pragma("unroll")                                                             \
    for (int c = 0; c < 2; ++c) {                                                 \
        const int R = w * 32 + c * 16;                                            \
        const int row = R + sr;                                                   \
        GLD_LDS16(Ag + (size_t)row * K + kk + ((sc ^ ((row >> 1) & 3)) << 3),     \
                  shA[b] + R * 32);                                               \
        GLD_LDS16(Wg + (size_t)row * K + kk + ((sc ^ ((row >> 1) & 3)) << 3),     \
                  shW[b] + R * 32);                                               \
    } }

#define MLP_STEP(t, vmstr, dostage) {                                             \
    const int p = (t) & 1;                                                        \
    bf16x8 af[4], bv[4];                                                          \
    _Pragma("unroll")                                                             \
    for (int i = 0; i < 4; ++i) {                                                 \
        const int ra = wm + i * 16 + lm;                                          \
        const int rb = wn + i * 16 + lm;                                          \
        af[i] = *(const bf16x8*)(shA[p] + ra * 32 + ((lg ^ ((ra >> 1) & 3)) << 3)); \
        bv[i] = *(const bf16x8*)(shW[p] + rb * 32 + ((lg ^ ((rb >> 1) & 3)) << 3)); \
    }                                                                             \
    asm volatile("s_waitcnt lgkmcnt(0)" ::: "memory");                            \
    __builtin_amdgcn_s_barrier();                                                 \
    if (dostage) MLP_STAGE(p, (t) + 2);                                           \
    __builtin_amdgcn_sched_barrier(0);                                            \
    _Pragma("unroll")                                                             \
    for (int i = 0; i < 4; ++i)                                                   \
        _Pragma("unroll")                                                         \
        for (int j = 0; j < 4; ++j)                                               \
            acc[i][j] = __builtin_amdgcn_mfma_f32_16x16x32_bf16(af[i], bv[j], acc[i][j], 0, 0, 0); \
    asm volatile(vmstr ::: "memory");                                             \
    __builtin_amdgcn_s_barrier();                                                 \
  }

    MLP_STAGE(0, 0)
    MLP_STAGE(1, 1)
    asm volatile("s_waitcnt vmcnt(4)" ::: "memory");
    __builtin_amdgcn_s_barrier();

    MLP_STEP(0,  "s_waitcnt vmcnt(4)", 1)
    MLP_STEP(1,  "s_waitcnt vmcnt(4)", 1)
    MLP_STEP(2,  "s_waitcnt vmcnt(4)", 1)
    MLP_STEP(3,  "s_waitcnt vmcnt(4)", 1)
    MLP_STEP(4,  "s_waitcnt vmcnt(4)", 1)
    MLP_STEP(5,  "s_waitcnt vmcnt(4)", 1)
    MLP_STEP(6,  "s_waitcnt vmcnt(4)", 1)
    MLP_STEP(7,  "s_waitcnt vmcnt(4)", 1)
    MLP_STEP(8,  "s_waitcnt vmcnt(4)", 1)
    MLP_STEP(9,  "s_waitcnt vmcnt(4)", 1)
    MLP_STEP(10, "s_waitcnt vmcnt(4)", 1)
    MLP_STEP(11, "s_waitcnt vmcnt(4)", 1)
    MLP_STEP(12, "s_waitcnt vmcnt(4)", 1)
    MLP_STEP(13, "s_waitcnt vmcnt(4)", 1)
    MLP_STEP(14, "s_waitcnt vmcnt(0)", 0)
    MLP_STEP(15, "s_waitcnt vmcnt(0)", 0)
#undef MLP_STEP
#undef MLP_STAGE

    // epilogue: C/D layout col = l&15, row = (l>>4)*4 + reg; nt stores keep
    // the 246 MB output stream out of L2 so W panels survive.
    #pragma unroll
    for (int j = 0; j < 4; ++j) {
        const int n = n0 + wn + j * 16 + lm;
        if (n >= N) continue;
        const float bj = bias[n];
        #pragma unroll
        for (int i = 0; i < 4; ++i) {
            const int m = m0 + wm + i * 16 + lg * 4;
            #pragma unroll
            for (int q = 0; q < 4; ++q)
                __builtin_nontemporal_store(acc[i][j][q] + bj, &C[(size_t)(m + q) * N + n]);
        }
    }
}

// ---------------------------------------------------------------------------
// K7: fused gate + blend: each wave redundantly computes gama for its row,
// then c_bf = bf16( g*s_t + (1-g)*r_t ). No sentinel kernel, no extra sync.
__global__ __launch_bounds__(256) void k_blend_gate(
    const float* __restrict__ s_t, const float* __restrict__ r_t,
    const float* __restrict__ Qh,
    const float* __restrict__ W_Ss, const float* __restrict__ b_Ss,
    const float* __restrict__ W_Sr, const float* __restrict__ b_Sr,
    const float* __restrict__ W_bq, const float* __restrict__ b_bq,
    const int* __restrict__ epoch, short* __restrict__ c_bf)
{
    const int row = blockIdx.x;
    const int s = row & 127;                 // gate row (batch 0, diagonal)
    const int t = threadIdx.x;
    float g = 1.0f;
    if (epoch[0] > 20) {
        const int l = t & 63;
        const int d = l * 8;
        const float4 s0 = *(const float4*)(s_t + (size_t)s * 512 + d);
        const float4 s1 = *(const float4*)(s_t + (size_t)s * 512 + d + 4);
        const float4 r0 = *(const float4*)(r_t + (size_t)s * 512 + d);
        const float4 r1 = *(const float4*)(r_t + (size_t)s * 512 + d + 4);
        float ss = b_bq[0], sr = b_bq[0];
        #pragma unroll
        for (int k = 0; k < 5; ++k) {
            const float4 w0 = *(const float4*)(W_Ss + k * 512 + d);
            const float4 w1 = *(const float4*)(W_Ss + k * 512 + d + 4);
            const float4 v0 = *(const float4*)(W_Sr + k * 512 + d);
            const float4 v1 = *(const float4*)(W_Sr + k * 512 + d + 4);
            float as = s0.x*w0.x + s0.y*w0.y + s0.z*w0.z + s0.w*w0.w
                     + s1.x*w1.x + s1.y*w1.y + s1.z*w1.z + s1.w*w1.w;
            float ar = r0.x*v0.x + r0.y*v0.y + r0.z*v0.z + r0.w*v0.w
                     + r1.x*v1.x + r1.y*v1.y + r1.z*v1.z + r1.w*v1.w;
            #pragma unroll
            for (int off = 32; off; off >>= 1) {
                as += __shfl_xor(as, off);
                ar += __shfl_xor(ar, off);
            }
            const float qh = Qh[s * 8 + k];
            ss += tanhf(as + b_Ss[k] + qh) * W_bq[k];
            sr += tanhf(ar + b_Sr[k] + qh) * W_bq[k];
        }
        g = 1.f / (1.f + expf(-(ss - sr)));
    }
    const size_t base = (size_t)row * 512;
    for (int i = t; i < 512; i += 256)
        c_bf[base + i] = f2bf(g * s_t[base + i] + (1.f - g) * r_t[base + i]);
}

// ---------------------------------------------------------------------------
extern "C" void kernel_launch(void* const* d_in, const int* in_sizes, int n_in,
                              void* d_out, int out_size, void* d_ws, size_t ws_size,
                              hipStream_t stream)
{
    const int*   epoch = (const int*)  d_in[0];
    const float* h_t   = (const float*)d_in[1];
    const float* V     = (const float*)d_in[2];
    const float* T     = (const float*)d_in[3];
    const float* W_ZV  = (const float*)d_in[4];  const float* b_ZV = (const float*)d_in[5];
    const float* W_Zh  = (const float*)d_in[6];  const float* b_Zh = (const float*)d_in[7];
    const float* W_az  = (const float*)d_in[8];  const float* b_az = (const float*)d_in[9];
    const float* W_QT  = (const float*)d_in[10]; const float* b_QT = (const float*)d_in[11];
    const float* W_Qh  = (const float*)d_in[12]; const float* b_Qh = (const float*)d_in[13];
    const float* W_bq  = (const float*)d_in[14]; const float* b_bq = (const float*)d_in[15];
    const float* W_sq  = (const float*)d_in[16]; const float* b_sq = (const float*)d_in[17];
    const float* W_sh  = (const float*)d_in[18]; const float* b_sh = (const float*)d_in[19];
    const float* W_Ss  = (const float*)d_in[20]; const float* b_Ss = (const float*)d_in[21];
    const float* W_Sr  = (const float*)d_in[22]; const float* b_Sr = (const float*)d_in[23];
    const float* W_sz  = (const float*)d_in[24]; const float* b_sz = (const float*)d_in[25];
    const float* W_mlp = (const float*)d_in[26]; const float* b_mlp= (const float*)d_in[27];

    float* out = (float*)d_out;
    float* ws  = (float*)d_ws;
    const size_t M1 = 1024 * 1024;        // 2048*512
    float* r_t  = ws;                     // 1M f
    float* s_t  = ws + M1;                // 1M f
    float* Zh   = ws + 2 * M1;            // 131072 f
    float* ZV   = Zh + 2048 * 64;         // 50176 f
    float* Qh   = ZV + 784 * 64;          // 16384 f
    float* QT   = Qh + 2048 * 8;          // 640 f
    float* pad  = QT + 80 * 8;            // 128 f (unused)
    short* sreg = (short*)(pad + 128);
    short* z_bf   = sreg;                 // 1M sh
    short* q_bf   = z_bf + M1;            // 1M sh
    short* h_bf   = q_bf + M1;            // 1M sh
    short* c_bf   = h_bf + M1;            // 1M sh
    short* Wsz_bf = c_bf + M1;            // 256K sh
    short* Wsq_bf = Wsz_bf + 512 * 512;
    short* Wsh_bf = Wsq_bf + 512 * 512;
    short* W_bf   = Wsh_bf + 512 * 512;   // 30080*512 sh (incl. 80-row pad)

    k_front<<<11308, 256, 0, stream>>>(h_t, V, T,
                                       W_Zh, b_Zh, W_Qh, b_Qh, W_ZV, b_ZV, W_QT, b_QT,
                                       Zh, Qh, ZV, QT,
                                       W_mlp, W_bf, h_bf,
                                       W_sz, Wsz_bf, W_sq, Wsq_bf, W_sh, Wsh_bf);
    k_attn<<<2048, 256, 0, stream>>>(V, T, ZV, Zh, QT, Qh, W_az, b_az, W_bq, b_bq, z_bf, q_bf);
    k_rs<<<dim3(32, 8), 256, 0, stream>>>(z_bf, q_bf, h_bf, Wsz_bf, Wsq_bf, Wsh_bf,
                                          b_sz, b_sq, b_sh, r_t, s_t);
    k_blend_gate<<<2048, 256, 0, stream>>>(s_t, r_t, Qh, W_Ss, b_Ss, W_Sr, b_Sr,
                                           W_bq, b_bq, epoch, c_bf);
    k_gemm_mlp<<<3760, 256, 0, stream>>>(c_bf, W_bf, b_mlp, out);
}

// Round 6
// 205.941 us; speedup vs baseline: 6.3214x; 1.0550x over previous
//
#include <hip/hip_runtime.h>
#include <hip/hip_bf16.h>

// Shapes: EMBED=HIDDEN=512, VOCAB=30000, B=16, S=128, K=49, NT=5, rows BS=2048

typedef short bf16x8 __attribute__((ext_vector_type(8)));
typedef float f32x4 __attribute__((ext_vector_type(4)));
typedef short short8 __attribute__((ext_vector_type(8)));

static __device__ __forceinline__ short f2bf(float f) {
    union { float f; unsigned u; } v; v.f = f;
    unsigned r = v.u + 0x7FFFu + ((v.u >> 16) & 1u);   // RNE
    return (short)(r >> 16);
}

#define GLD_LDS16(gp, lp)                                                          \
    __builtin_amdgcn_global_load_lds(                                              \
        (const __attribute__((address_space(1))) unsigned int*)(gp),               \
        (__attribute__((address_space(3))) unsigned int*)(lp), 16, 0, 0)

// ---------------------------------------------------------------------------
// K_front: fused independent front work, critical-path blocks first.
__global__ __launch_bounds__(256) void k_front(
    const float* __restrict__ h, const float* __restrict__ V, const float* __restrict__ T,
    const float* __restrict__ W_Zh, const float* __restrict__ b_Zh,
    const float* __restrict__ W_Qh, const float* __restrict__ b_Qh,
    const float* __restrict__ W_ZV, const float* __restrict__ b_ZV,
    const float* __restrict__ W_QT, const float* __restrict__ b_QT,
    float* __restrict__ Zh, float* __restrict__ Qh,
    float* __restrict__ ZV, float* __restrict__ QT,
    const float* __restrict__ wmlp, short* __restrict__ wmlp_b,
    short* __restrict__ h_b,
    const float* __restrict__ wsz, short* __restrict__ wsz_b,
    const float* __restrict__ wsq, short* __restrict__ wsq_b,
    const float* __restrict__ wsh, short* __restrict__ wsh_b)
{
    __shared__ float xs[512];
    const int bid = blockIdx.x;
    const int t = threadIdx.x;

    if (bid < 2048) {                         // lin_h
        const float* hp = h + (size_t)bid * 512;
        for (int i = t; i < 512; i += 256) xs[i] = hp[i];
        __syncthreads();
        if (t < 49) {
            const float* w = W_Zh + t * 512;
            float acc = b_Zh[t];
            #pragma unroll 8
            for (int i = 0; i < 512; ++i) acc = fmaf(xs[i], w[i], acc);
            Zh[bid * 64 + t] = acc;
        } else if (t >= 64 && t < 69) {
            const int o = t - 64;
            const float* w = W_Qh + o * 512;
            float acc = b_Qh[o];
            #pragma unroll 8
            for (int i = 0; i < 512; ++i) acc = fmaf(xs[i], w[i], acc);
            Qh[bid * 8 + o] = acc;
        }
        return;
    }
    if (bid < 2912) {                         // lin_vt
        const int blk = bid - 2048;
        if (blk < 784) {
            const float* xp = V + (size_t)blk * 512;
            for (int i = t; i < 512; i += 256) xs[i] = xp[i];
            __syncthreads();
            if (t < 49) {
                const float* w = W_ZV + t * 512;
                float acc = b_ZV[t];
                #pragma unroll 8
                for (int i = 0; i < 512; ++i) acc = fmaf(xs[i], w[i], acc);
                ZV[blk * 64 + t] = acc;
            }
        } else {
            const int row = blk - 784;
            const float* xp = T + (size_t)row * 512;
            for (int i = t; i < 512; i += 256) xs[i] = xp[i];
            __syncthreads();
            if (t < 5) {
                const float* w = W_QT + t * 512;
                float acc = b_QT[t];
                #pragma unroll 8
                for (int i = 0; i < 512; ++i) acc = fmaf(xs[i], w[i], acc);
                QT[row * 8 + t] = acc;
            }
        }
        return;
    }
    // cvt sections
    const float* src; short* dst; int i;
    if (bid < 10412)      { src = wmlp; dst = wmlp_b; i = (bid - 2912) * 256 + t; }
    else if (bid < 10924) { src = h;    dst = h_b;    i = (bid - 10412) * 256 + t; }
    else if (bid < 11052) { src = wsz;  dst = wsz_b;  i = (bid - 10924) * 256 + t; }
    else if (bid < 11180) { src = wsq;  dst = wsq_b;  i = (bid - 11052) * 256 + t; }
    else                  { src = wsh;  dst = wsh_b;  i = (bid - 11180) * 256 + t; }
    const float4 a = ((const float4*)src)[i * 2];
    const float4 b = ((const float4*)src)[i * 2 + 1];
    short8 o;
    o[0] = f2bf(a.x); o[1] = f2bf(a.y); o[2] = f2bf(a.z); o[3] = f2bf(a.w);
    o[4] = f2bf(b.x); o[5] = f2bf(b.y); o[6] = f2bf(b.z); o[7] = f2bf(b.w);
    ((short8*)dst)[i] = o;
}

// ---------------------------------------------------------------------------
// K3: per (b,s): visual + topic attention -> z_bf, q_bf (2048,512) bf16
// Softmaxes are wave-parallel (shfl_xor reduce) instead of single-lane serial.
__global__ void k_attn(const float* __restrict__ V, const float* __restrict__ T,
                       const float* __restrict__ ZV, const float* __restrict__ Zh,
                       const float* __restrict__ QT, const float* __restrict__ Qh,
                       const float* __restrict__ W_az, const float* __restrict__ b_az,
                       const float* __restrict__ W_bq, const float* __restrict__ b_bq,
                       short* __restrict__ z_bf, short* __restrict__ q_bf)
{
    const int row = blockIdx.x;       // b*128+s
    const int b = row >> 7;
    const int t = threadIdx.x;
    __shared__ float zh[49], waz[49], alpha[49], beta[5];
    if (t < 49) { zh[t] = Zh[row * 64 + t]; waz[t] = W_az[t]; }
    __syncthreads();
    if (t < 49) {
        const float* zv = ZV + (b * 49 + t) * 64;
        float acc = b_az[0];
        for (int j = 0; j < 49; ++j) acc += tanhf(zv[j] + zh[j]) * waz[j];
        alpha[t] = acc;
    } else if (t >= 64 && t < 69) {
        const int tt = t - 64;
        const float* qt = QT + (b * 5 + tt) * 8;
        const float* qh = Qh + row * 8;
        float acc = b_bq[0];
        for (int j = 0; j < 5; ++j) acc += tanhf(qt[j] + qh[j]) * W_bq[j];
        beta[tt] = acc;
    }
    __syncthreads();
    const int wv = t >> 6, l = t & 63;
    if (wv == 0) {                       // softmax over 49, wave-parallel
        float a = (l < 49) ? alpha[l] : -1e30f;
        float m = a;
        #pragma unroll
        for (int off = 32; off; off >>= 1) m = fmaxf(m, __shfl_xor(m, off));
        float e = (l < 49) ? expf(a - m) : 0.f;
        float s = e;
        #pragma unroll
        for (int off = 32; off; off >>= 1) s += __shfl_xor(s, off);
        if (l < 49) alpha[l] = e / s;
    } else if (wv == 1) {                // softmax over 5, wave-parallel
        float a = (l < 5) ? beta[l] : -1e30f;
        float m = a;
        #pragma unroll
        for (int off = 32; off; off >>= 1) m = fmaxf(m, __shfl_xor(m, off));
        float e = (l < 5) ? expf(a - m) : 0.f;
        float s = e;
        #pragma unroll
        for (int off = 32; off; off >>= 1) s += __shfl_xor(s, off);
        if (l < 5) beta[l] = e / s;
    }
    __syncthreads();
    const float* Vb = V + (size_t)b * 49 * 512;
    const float* Tb = T + (size_t)b * 5 * 512;
    for (int hd = t; hd < 512; hd += 256) {
        float az = 0.f;
        #pragma unroll
        for (int k = 0; k < 49; ++k) az = fmaf(alpha[k], Vb[k * 512 + hd], az);
        z_bf[(size_t)row * 512 + hd] = f2bf(az);
        float aq = 0.f;
        #pragma unroll
        for (int k = 0; k < 5; ++k) aq = fmaf(beta[k], Tb[k * 512 + hd], aq);
        q_bf[(size_t)row * 512 + hd] = f2bf(aq);
    }
}

// ---------------------------------------------------------------------------
// K4: r_t = tanh(z@Wsz.T + b_sz), s_t = tanh(q@Wsq.T + h@Wsh.T + b_sq + b_sh)
__global__ __launch_bounds__(256) void k_rs(
    const short* __restrict__ Zb, const short* __restrict__ Qb, const short* __restrict__ Hb,
    const short* __restrict__ Wsz, const short* __restrict__ Wsq, const short* __restrict__ Wsh,
    const float* __restrict__ b_sz, const float* __restrict__ b_sq, const float* __restrict__ b_sh,
    float* __restrict__ r_t, float* __restrict__ s_t)
{
    constexpr int K = 512, NN = 512;
    __shared__ __align__(16) short sA[64 * 64];
    __shared__ __align__(16) short sW[64 * 64];
    const int tid = threadIdx.x;
    const int l = tid & 63, w = tid >> 6;
    const int m0 = blockIdx.x * 64, n0 = blockIdx.y * 64;
    const int wm = (w & 1) * 32, wn = (w >> 1) * 32;
    const int lm = l & 15, lg = l >> 4;
    const int sr = l >> 3, sc = l & 7;
    f32x4 accr[2][2] = {}, accs[2][2] = {};

#define RS_PASS(AG, WG, ACC)                                                      \
    for (int k0 = 0; k0 < K; k0 += 64) {                                          \
        _Pragma("unroll")                                                         \
        for (int c = 0; c < 2; ++c) {                                             \
            const int R = w * 16 + c * 8;                                         \
            const int row = R + sr;                                               \
            GLD_LDS16((AG) + (size_t)(m0 + row) * K + k0 + ((sc ^ (row & 7)) << 3), sA + R * 64); \
            GLD_LDS16((WG) + (size_t)(n0 + row) * K + k0 + ((sc ^ (row & 7)) << 3), sW + R * 64); \
        }                                                                         \
        __syncthreads();                                                          \
        bf16x8 af[2][2], bv[2][2];                                                \
        _Pragma("unroll")                                                         \
        for (int s = 0; s < 2; ++s)                                               \
            _Pragma("unroll")                                                     \
            for (int i = 0; i < 2; ++i) {                                         \
                const int ra = wm + i * 16 + lm;                                  \
                const int rb = wn + i * 16 + lm;                                  \
                af[s][i] = *(const bf16x8*)(sA + ra * 64 + (((s * 4 + lg) ^ (ra & 7)) << 3)); \
                bv[s][i] = *(const bf16x8*)(sW + rb * 64 + (((s * 4 + lg) ^ (rb & 7)) << 3)); \
            }                                                                     \
        _Pragma("unroll")                                                         \
        for (int s = 0; s < 2; ++s)                                               \
            _Pragma("unroll")                                                     \
            for (int i = 0; i < 2; ++i)                                           \
                _Pragma("unroll")                                                 \
                for (int j = 0; j < 2; ++j)                                       \
                    ACC[i][j] = __builtin_amdgcn_mfma_f32_16x16x32_bf16(af[s][i], bv[s][j], ACC[i][j], 0, 0, 0); \
        __syncthreads();                                                          \
    }

    RS_PASS(Zb, Wsz, accr)
    RS_PASS(Qb, Wsq, accs)
    RS_PASS(Hb, Wsh, accs)
#undef RS_PASS

    #pragma unroll
    for (int j = 0; j < 2; ++j) {
        const int n = n0 + wn + j * 16 + lm;
        const float br = b_sz[n];
        const float bs = b_sq[n] + b_sh[n];
        #pragma unroll
        for (int i = 0; i < 2; ++i) {
            const int m = m0 + wm + i * 16 + lg * 4;
            #pragma unroll
            for (int q = 0; q < 4; ++q) {
                r_t[(size_t)(m + q) * NN + n] = tanhf(accr[i][j][q] + br);
                s_t[(size_t)(m + q) * NN + n] = tanhf(accs[i][j][q] + bs);
            }
        }
    }
}

// ---------------------------------------------------------------------------
// K5: MLP GEMM: 128x128 tile, BK=64 double-buffered, counted vmcnt(8),
// stage-before-MFMA overlap, setprio around MFMA, T1 XCD swizzle, nt stores.
__global__ __launch_bounds__(256) void k_gemm_mlp(
    const short* __restrict__ A, const short* __restrict__ Wb,
    const float* __restrict__ bias, float* __restrict__ C)
{
    constexpr int N = 30000, K = 512;
    __shared__ __align__(16) short shA[2][128 * 64];   // 16 KB each
    __shared__ __align__(16) short shW[2][128 * 64];   // total 64 KB
    const int tid = threadIdx.x;
    const int l = tid & 63, w = tid >> 6;
    const int bid = blockIdx.x;
    const int swz = (bid & 7) * 470 + (bid >> 3);      // bijective (3760%8==0)
    const int m0 = (swz & 15) * 128;                   // m fast -> W panel reuse
    const int n0 = (swz >> 4) * 128;
    const int wm = (w & 1) * 64, wn = (w >> 1) * 64;
    const int lm = l & 15, lg = l >> 4;
    const int sr = tid >> 3, sc = tid & 7;             // staging row(32/call), chunk
    const short* Ag = A  + (size_t)m0 * K;
    const short* Wg = Wb + (size_t)n0 * K;
    f32x4 acc[4][4] = {};

// Stage tile t (BK=64) into buffer p: 4 calls x 2 operands = 8 gld_lds/thread.
// LDS linear; global source chunk pre-swizzled (chunk ^ row&7, involution).
#define MLP_STAGE(p, t) {                                                         \
    const int kk = (t) * 64;                                                      \
    _Pragma("unroll")                                                             \
    for (int c = 0; c < 4; ++c) {                                                 \
        const int row = c * 32 + sr;                                              \
        GLD_LDS16(Ag + (size_t)row * K + kk + ((sc ^ (row & 7)) << 3),            \
                  &shA[p][(c * 32 + w * 8) * 64]);                                \
        GLD_LDS16(Wg + (size_t)row * K + kk + ((sc ^ (row & 7)) << 3),            \
                  &shW[p][(c * 32 + w * 8) * 64]);                                \
    } }

// One K-step: wait own tile loads -> barrier -> ds_read -> lgkm(0) -> barrier
// (buf free) -> stage t+2 (in flight under MFMA) -> 32 MFMA under setprio.
#define MLP_STEP(t, vmstr, dostage) {                                             \
    const int p = (t) & 1;                                                        \
    asm volatile(vmstr ::: "memory");                                             \
    __builtin_amdgcn_s_barrier();                                                 \
    bf16x8 af[2][4], bv[2][4];                                                    \
    _Pragma("unroll")                                                             \
    for (int s = 0; s < 2; ++s)                                                   \
      _Pragma("unroll")                                                           \
      for (int i = 0; i < 4; ++i) {                                               \
        const int ra = wm + i * 16 + lm;                                          \
        const int rb = wn + i * 16 + lm;                                          \
        const int ck = s * 4 + lg;                                                \
        af[s][i] = *(const bf16x8*)(&shA[p][ra * 64 + ((ck ^ (ra & 7)) << 3)]);   \
        bv[s][i] = *(const bf16x8*)(&shW[p][rb * 64 + ((ck ^ (rb & 7)) << 3)]);   \
      }                                                                           \
    asm volatile("s_waitcnt lgkmcnt(0)" ::: "memory");                            \
    __builtin_amdgcn_s_barrier();                                                 \
    if (dostage) MLP_STAGE(p, (t) + 2);                                           \
    __builtin_amdgcn_sched_barrier(0);                                            \
    __builtin_amdgcn_s_setprio(1);                                                \
    _Pragma("unroll")                                                             \
    for (int s = 0; s < 2; ++s)                                                   \
      _Pragma("unroll")                                                           \
      for (int i = 0; i < 4; ++i)                                                 \
        _Pragma("unroll")                                                         \
        for (int j = 0; j < 4; ++j)                                               \
            acc[i][j] = __builtin_amdgcn_mfma_f32_16x16x32_bf16(af[s][i], bv[s][j], acc[i][j], 0, 0, 0); \
    __builtin_amdgcn_s_setprio(0);                                                \
  }

    MLP_STAGE(0, 0)
    MLP_STAGE(1, 1)

    MLP_STEP(0, "s_waitcnt vmcnt(8)", 1)
    MLP_STEP(1, "s_waitcnt vmcnt(8)", 1)
    MLP_STEP(2, "s_waitcnt vmcnt(8)", 1)
    MLP_STEP(3, "s_waitcnt vmcnt(8)", 1)
    MLP_STEP(4, "s_waitcnt vmcnt(8)", 1)
    MLP_STEP(5, "s_waitcnt vmcnt(8)", 1)
    MLP_STEP(6, "s_waitcnt vmcnt(8)", 0)
    MLP_STEP(7, "s_waitcnt vmcnt(0)", 0)
#undef MLP_STEP
#undef MLP_STAGE

    // epilogue: C/D layout col = l&15, row = (l>>4)*4 + reg; nt stores keep
    // the 246 MB output stream out of L2 so W panels survive.
    #pragma unroll
    for (int j = 0; j < 4; ++j) {
        const int n = n0 + wn + j * 16 + lm;
        if (n >= N) continue;
        const float bj = bias[n];
        #pragma unroll
        for (int i = 0; i < 4; ++i) {
            const int m = m0 + wm + i * 16 + lg * 4;
            #pragma unroll
            for (int q = 0; q < 4; ++q)
                __builtin_nontemporal_store(acc[i][j][q] + bj, &C[(size_t)(m + q) * N + n]);
        }
    }
}

// ---------------------------------------------------------------------------
// K7: fused gate + blend: each block recomputes gama for its row, then
// c_bf = bf16( g*s_t + (1-g)*r_t ).
__global__ __launch_bounds__(256) void k_blend_gate(
    const float* __restrict__ s_t, const float* __restrict__ r_t,
    const float* __restrict__ Qh,
    const float* __restrict__ W_Ss, const float* __restrict__ b_Ss,
    const float* __restrict__ W_Sr, const float* __restrict__ b_Sr,
    const float* __restrict__ W_bq, const float* __restrict__ b_bq,
    const int* __restrict__ epoch, short* __restrict__ c_bf)
{
    const int row = blockIdx.x;
    const int s = row & 127;                 // gate row (batch 0, diagonal)
    const int t = threadIdx.x;
    float g = 1.0f;
    if (epoch[0] > 20) {
        const int l = t & 63;
        const int d = l * 8;
        const float4 s0 = *(const float4*)(s_t + (size_t)s * 512 + d);
        const float4 s1 = *(const float4*)(s_t + (size_t)s * 512 + d + 4);
        const float4 r0 = *(const float4*)(r_t + (size_t)s * 512 + d);
        const float4 r1 = *(const float4*)(r_t + (size_t)s * 512 + d + 4);
        float ss = b_bq[0], sr = b_bq[0];
        #pragma unroll
        for (int k = 0; k < 5; ++k) {
            const float4 w0 = *(const float4*)(W_Ss + k * 512 + d);
            const float4 w1 = *(const float4*)(W_Ss + k * 512 + d + 4);
            const float4 v0 = *(const float4*)(W_Sr + k * 512 + d);
            const float4 v1 = *(const float4*)(W_Sr + k * 512 + d + 4);
            float as = s0.x*w0.x + s0.y*w0.y + s0.z*w0.z + s0.w*w0.w
                     + s1.x*w1.x + s1.y*w1.y + s1.z*w1.z + s1.w*w1.w;
            float ar = r0.x*v0.x + r0.y*v0.y + r0.z*v0.z + r0.w*v0.w
                     + r1.x*v1.x + r1.y*v1.y + r1.z*v1.z + r1.w*v1.w;
            #pragma unroll
            for (int off = 32; off; off >>= 1) {
                as += __shfl_xor(as, off);
                ar += __shfl_xor(ar, off);
            }
            const float qh = Qh[s * 8 + k];
            ss += tanhf(as + b_Ss[k] + qh) * W_bq[k];
            sr += tanhf(ar + b_Sr[k] + qh) * W_bq[k];
        }
        g = 1.f / (1.f + expf(-(ss - sr)));
    }
    const size_t base = (size_t)row * 512;
    for (int i = t; i < 512; i += 256)
        c_bf[base + i] = f2bf(g * s_t[base + i] + (1.f - g) * r_t[base + i]);
}

// ---------------------------------------------------------------------------
extern "C" void kernel_launch(void* const* d_in, const int* in_sizes, int n_in,
                              void* d_out, int out_size, void* d_ws, size_t ws_size,
                              hipStream_t stream)
{
    const int*   epoch = (const int*)  d_in[0];
    const float* h_t   = (const float*)d_in[1];
    const float* V     = (const float*)d_in[2];
    const float* T     = (const float*)d_in[3];
    const float* W_ZV  = (const float*)d_in[4];  const float* b_ZV = (const float*)d_in[5];
    const float* W_Zh  = (const float*)d_in[6];  const float* b_Zh = (const float*)d_in[7];
    const float* W_az  = (const float*)d_in[8];  const float* b_az = (const float*)d_in[9];
    const float* W_QT  = (const float*)d_in[10]; const float* b_QT = (const float*)d_in[11];
    const float* W_Qh  = (const float*)d_in[12]; const float* b_Qh = (const float*)d_in[13];
    const float* W_bq  = (const float*)d_in[14]; const float* b_bq = (const float*)d_in[15];
    const float* W_sq  = (const float*)d_in[16]; const float* b_sq = (const float*)d_in[17];
    const float* W_sh  = (const float*)d_in[18]; const float* b_sh = (const float*)d_in[19];
    const float* W_Ss  = (const float*)d_in[20]; const float* b_Ss = (const float*)d_in[21];
    const float* W_Sr  = (const float*)d_in[22]; const float* b_Sr = (const float*)d_in[23];
    const float* W_sz  = (const float*)d_in[24]; const float* b_sz = (const float*)d_in[25];
    const float* W_mlp = (const float*)d_in[26]; const float* b_mlp= (const float*)d_in[27];

    float* out = (float*)d_out;
    float* ws  = (float*)d_ws;
    const size_t M1 = 1024 * 1024;        // 2048*512
    float* r_t  = ws;                     // 1M f
    float* s_t  = ws + M1;                // 1M f
    float* Zh   = ws + 2 * M1;            // 131072 f
    float* ZV   = Zh + 2048 * 64;         // 50176 f
    float* Qh   = ZV + 784 * 64;          // 16384 f
    float* QT   = Qh + 2048 * 8;          // 640 f
    float* pad  = QT + 80 * 8;            // 128 f (unused)
    short* sreg = (short*)(pad + 128);
    short* z_bf   = sreg;                 // 1M sh
    short* q_bf   = z_bf + M1;            // 1M sh
    short* h_bf   = q_bf + M1;            // 1M sh
    short* c_bf   = h_bf + M1;            // 1M sh
    short* Wsz_bf = c_bf + M1;            // 256K sh
    short* Wsq_bf = Wsz_bf + 512 * 512;
    short* Wsh_bf = Wsq_bf + 512 * 512;
    short* W_bf   = Wsh_bf + 512 * 512;   // 30080*512 sh (incl. 80-row pad)

    k_front<<<11308, 256, 0, stream>>>(h_t, V, T,
                                       W_Zh, b_Zh, W_Qh, b_Qh, W_ZV, b_ZV, W_QT, b_QT,
                                       Zh, Qh, ZV, QT,
                                       W_mlp, W_bf, h_bf,
                                       W_sz, Wsz_bf, W_sq, Wsq_bf, W_sh, Wsh_bf);
    k_attn<<<2048, 256, 0, stream>>>(V, T, ZV, Zh, QT, Qh, W_az, b_az, W_bq, b_bq, z_bf, q_bf);
    k_rs<<<dim3(32, 8), 256, 0, stream>>>(z_bf, q_bf, h_bf, Wsz_bf, Wsq_bf, Wsh_bf,
                                          b_sz, b_sq, b_sh, r_t, s_t);
    k_blend_gate<<<2048, 256, 0, stream>>>(s_t, r_t, Qh, W_Ss, b_Ss, W_Sr, b_Sr,
                                           W_bq, b_bq, epoch, c_bf);
    k_gemm_mlp<<<3760, 256, 0, stream>>>(c_bf, W_bf, b_mlp, out);
}